// Round 8
// baseline (250.822 us; speedup 1.0000x reference)
//
#include <hip/hip_runtime.h>
#include <math.h>

#define L_SEQ  2048
#define D_MODEL 1024
#define N_HEAD 16
#define D_HEAD 64
#define B_SIZE 2

typedef __attribute__((ext_vector_type(8))) short bf16x8;
typedef __attribute__((ext_vector_type(4))) float f32x4;
typedef unsigned short u16;
typedef unsigned int u32;

__device__ __forceinline__ f32x4 mfma16(bf16x8 a, bf16x8 b, f32x4 c) {
    return __builtin_amdgcn_mfma_f32_16x16x32_bf16(a, b, c, 0, 0, 0);
}

__device__ __forceinline__ u16 f2bf(float x) {
    u32 u = __builtin_bit_cast(u32, x);
    u32 r = (u + 0x7FFFu + ((u >> 16) & 1u)) >> 16;
    return (u16)r;
}
__device__ __forceinline__ u16 f2bf_t(float x) {  // truncate (P only)
    return (u16)(__builtin_bit_cast(u32, x) >> 16);
}
__device__ __forceinline__ float bf2f(u16 h) {
    u32 u = ((u32)h) << 16;
    return __builtin_bit_cast(float, u);
}

__device__ __forceinline__ void gl2lds16(const void* g, void* l) {
    __builtin_amdgcn_global_load_lds(
        (__attribute__((address_space(1))) void*)(g),
        (__attribute__((address_space(3))) void*)(l), 16, 0, 0);
}

// ---------------------------------------------------------------------------
// split fp32 -> [hi | lo] bf16, row length K=1024 -> 2048.
// ---------------------------------------------------------------------------
__global__ __launch_bounds__(256) void split_hl(const float* __restrict__ in,
                                                u16* __restrict__ out) {
    const int idx = blockIdx.x * 256 + threadIdx.x;
    const int c4 = idx << 2;
    const int r = c4 >> 10, c = c4 & 1023;
    float4 v = *(const float4*)(in + c4);
    u16 h0 = f2bf(v.x), h1 = f2bf(v.y), h2 = f2bf(v.z), h3 = f2bf(v.w);
    ushort4 hi = make_ushort4(h0, h1, h2, h3);
    ushort4 lo = make_ushort4(f2bf(v.x - bf2f(h0)), f2bf(v.y - bf2f(h1)),
                              f2bf(v.z - bf2f(h2)), f2bf(v.w - bf2f(h3)));
    *(ushort4*)(out + (size_t)r * 2048 + c) = hi;
    *(ushort4*)(out + (size_t)r * 2048 + 1024 + c) = lo;
}

// fused 4-weight split
__global__ __launch_bounds__(256) void split_w4(
    const float* __restrict__ w0, const float* __restrict__ w1,
    const float* __restrict__ w2, const float* __restrict__ w3,
    u16* __restrict__ outbase) {
    const float* in = (blockIdx.y == 0) ? w0 : (blockIdx.y == 1) ? w1
                      : (blockIdx.y == 2) ? w2 : w3;
    u16* out = outbase + (size_t)blockIdx.y * 2097152;
    const int idx = blockIdx.x * 256 + threadIdx.x;
    const int c4 = idx << 2;
    const int r = c4 >> 10, c = c4 & 1023;
    float4 v = *(const float4*)(in + c4);
    u16 h0 = f2bf(v.x), h1 = f2bf(v.y), h2 = f2bf(v.z), h3 = f2bf(v.w);
    ushort4 hi = make_ushort4(h0, h1, h2, h3);
    ushort4 lo = make_ushort4(f2bf(v.x - bf2f(h0)), f2bf(v.y - bf2f(h1)),
                              f2bf(v.z - bf2f(h2)), f2bf(v.w - bf2f(h3)));
    *(ushort4*)(out + (size_t)r * 2048 + c) = hi;
    *(ushort4*)(out + (size_t)r * 2048 + 1024 + c) = lo;
}

// ---------------------------------------------------------------------------
// 8-phase 256x256 QKV GEMM (T3+T4 counted-vmcnt + T2 swizzle + T5 setprio).
// Fused N=3072 (Wq|Wk|Wv stacked), virtual K=3072 (hi/lo region map).
// 512 thr / 8 waves (2M x 4N); per-wave 128x64 out; BK=64; LDS 128 KB.
// Staging 3 half-tiles ahead; steady-state s_waitcnt vmcnt(4), never 0.
// Phase: [ds_read; stage 1 half-tile; bar; MFMA x16; bar].
// ---------------------------------------------------------------------------
__device__ __forceinline__ int kaOf(int x) {
    return (((x >> 4) == 1) ? 1024 : 0) + ((x << 6) & 1023);
}
__device__ __forceinline__ int kwOf(int x) {
    return (((x >> 4) == 0) ? 1024 : 0) + ((x << 6) & 1023);
}

#define SBAR()  do { __builtin_amdgcn_sched_barrier(0); \
                     __builtin_amdgcn_s_barrier(); \
                     __builtin_amdgcn_sched_barrier(0); } while (0)

__global__ __launch_bounds__(512) void gemm256_qkv(
    const u16* __restrict__ A2, const u16* __restrict__ Wall,
    u16* __restrict__ Qh, u16* __restrict__ Ql,
    u16* __restrict__ Kh, u16* __restrict__ Kl,
    u16* __restrict__ Vh) {
    extern __shared__ __align__(16) u16 smem[];  // [A0|B0|A1|B1] x 16384 u16

    const int t = threadIdx.x, l = t & 63, wid = t >> 6;
    const int id = blockIdx.x;                  // 192 blocks = 8 XCD x 24
    const int wg = (id & 7) * 24 + (id >> 3);   // bijective (192 % 8 == 0)
    const int mt = wg / 12, ntile = wg % 12;
    const int m0 = mt << 8, n0 = ntile << 8;

    const int wrH = wid >> 2;            // A half (0/1)
    const int wc = (wid & 3) << 6;       // wave col base within 256
    const int bHalf = (wid & 3) >> 1;    // B half
    const int brB = (wid & 1) << 6;      // row base within B half

    f32x4 acc[8][4];
#pragma unroll
    for (int i = 0; i < 8; ++i)
#pragma unroll
        for (int j = 0; j < 4; ++j) acc[i][j] = (f32x4){0.f, 0.f, 0.f, 0.f};

    const int sr = t >> 3, sc = t & 7;   // staging row/chunk

    auto stageA = [&](int x, int half) {
        const int koff = kaOf(x);
        u16* dst = smem + ((x & 1) * 32768) + half * 8192;
        const u16* srcb = A2 + (size_t)(m0 + half * 128) * 2048 + koff;
#pragma unroll
        for (int p = 0; p < 2; ++p) {
            const int r = sr + p * 64;
            const int ck = sc ^ (r & 7);
            gl2lds16(srcb + (size_t)r * 2048 + ck * 8, dst + (t + p * 512) * 8);
        }
    };
    auto stageB = [&](int x, int half) {
        const int koff = kwOf(x);
        u16* dst = smem + 16384 + ((x & 1) * 32768) + half * 8192;
        const u16* srcb = Wall + (size_t)(n0 + half * 128) * 2048 + koff;
#pragma unroll
        for (int p = 0; p < 2; ++p) {
            const int r = sr + p * 64;
            const int ck = sc ^ (r & 7);
            gl2lds16(srcb + (size_t)r * 2048 + ck * 8, dst + (t + p * 512) * 8);
        }
    };
    auto dsA = [&](int s, int mh, int kc, bf16x8 af[4]) {
        const u16* Ab = smem + s * 32768 + wrH * 8192;
#pragma unroll
        for (int f = 0; f < 4; ++f) {
            const int r = mh * 64 + f * 16 + (l & 15);
            const int c8 = kc * 4 + (l >> 4);
            af[f] = *(const bf16x8*)&Ab[r * 64 + ((c8 ^ (r & 7)) << 3)];
        }
    };
    auto dsB = [&](int s, int kc, bf16x8 bfr[4]) {
        const u16* Bb = smem + 16384 + s * 32768 + bHalf * 8192;
#pragma unroll
        for (int f = 0; f < 4; ++f) {
            const int r = brB + f * 16 + (l & 15);
            const int c8 = kc * 4 + (l >> 4);
            bfr[f] = *(const bf16x8*)&Bb[r * 64 + ((c8 ^ (r & 7)) << 3)];
        }
    };

    // prologue: tile0 (B,B,A,A) + tile1 (B,B) -> 12 loads/thread; wait oldest 8
    stageB(0, 0); stageB(0, 1); stageA(0, 0); stageA(0, 1);
    stageB(1, 0); stageB(1, 1);
    __builtin_amdgcn_sched_barrier(0);
    asm volatile("s_waitcnt vmcnt(4)" ::: "memory");
    __builtin_amdgcn_s_barrier();
    __builtin_amdgcn_sched_barrier(0);

    const int NT = 48;
    bf16x8 breg0[4], breg1[4], af[4];
    for (int tt = 0; tt < NT; ++tt) {
        const int s = tt & 1;
        // ---- q0: mh0 kc0 (load B kc0); stage t+1 Ah0 ----
        dsA(s, 0, 0, af); dsB(s, 0, breg0);
        if (tt + 1 < NT) stageA(tt + 1, 0);
        SBAR();
        __builtin_amdgcn_s_setprio(1);
#pragma unroll
        for (int f = 0; f < 4; ++f)
#pragma unroll
            for (int fn = 0; fn < 4; ++fn)
                acc[f][fn] = mfma16(af[f], breg0[fn], acc[f][fn]);
        __builtin_amdgcn_s_setprio(0);
        SBAR();
        // ---- q1: mh0 kc1 (load B kc1); stage t+1 Ah1 ----
        dsA(s, 0, 1, af); dsB(s, 1, breg1);
        if (tt + 1 < NT) stageA(tt + 1, 1);
        SBAR();
        __builtin_amdgcn_s_setprio(1);
#pragma unroll
        for (int f = 0; f < 4; ++f)
#pragma unroll
            for (int fn = 0; fn < 4; ++fn)
                acc[f][fn] = mfma16(af[f], breg1[fn], acc[f][fn]);
        __builtin_amdgcn_s_setprio(0);
        SBAR();
        // ---- q2: mh1 kc0 (B from regs); stage t+2 Bh0 (B freed after q1) ----
        dsA(s, 1, 0, af);
        if (tt + 2 < NT) stageB(tt + 2, 0);
        SBAR();
        __builtin_amdgcn_s_setprio(1);
#pragma unroll
        for (int f = 0; f < 4; ++f)
#pragma unroll
            for (int fn = 0; fn < 4; ++fn)
                acc[4 + f][fn] = mfma16(af[f], breg0[fn], acc[4 + f][fn]);
        __builtin_amdgcn_s_setprio(0);
        SBAR();
        // ---- q3: mh1 kc1; stage t+2 Bh1; boundary counted vmcnt ----
        dsA(s, 1, 1, af);
        if (tt + 2 < NT) stageB(tt + 2, 1);
        SBAR();
        __builtin_amdgcn_s_setprio(1);
#pragma unroll
        for (int f = 0; f < 4; ++f)
#pragma unroll
            for (int fn = 0; fn < 4; ++fn)
                acc[4 + f][fn] = mfma16(af[f], breg1[fn], acc[4 + f][fn]);
        __builtin_amdgcn_s_setprio(0);
        __builtin_amdgcn_sched_barrier(0);
        if (tt + 2 < NT) {
            asm volatile("s_waitcnt vmcnt(4)" ::: "memory");
        } else if (tt + 1 < NT) {
            asm volatile("s_waitcnt vmcnt(0)" ::: "memory");
        }
        __builtin_amdgcn_s_barrier();
        __builtin_amdgcn_sched_barrier(0);
    }

    // ---- epilogue: head-major split bf16 scatter (Q scaled; V hi-only) ----
#pragma unroll
    for (int fm = 0; fm < 8; ++fm)
#pragma unroll
        for (int fn = 0; fn < 4; ++fn)
#pragma unroll
            for (int rg = 0; rg < 4; ++rg) {
                const int gm = m0 + wrH * 128 + fm * 16 + ((l >> 4) << 2) + rg;
                const int gn = n0 + wc + fn * 16 + (l & 15);
                const int z = gn >> 10, col = gn & 1023;
                float v = acc[fm][fn][rg];
                if (z == 0) v *= 0.125f;  // fold 1/sqrt(dh) into Q
                const int b = gm >> 11, lq = gm & 2047;
                const int h = col >> 6, d = col & 63;
                const size_t oi = (((size_t)(b * 16 + h)) * 2048 + lq) * 64 + d;
                const u16 hi = f2bf(v);
                if (z == 0) { Qh[oi] = hi; Ql[oi] = f2bf(v - bf2f(hi)); }
                else if (z == 1) { Kh[oi] = hi; Kl[oi] = f2bf(v - bf2f(hi)); }
                else { Vh[oi] = hi; }
            }
}

// ---------------------------------------------------------------------------
// bf16x3-emulated fp32 GEMM (R4 config) — used for the Wo projection.
// ---------------------------------------------------------------------------
template <int MODE>
__global__ __launch_bounds__(256) void gemm_ks(
    const u16* __restrict__ A2, const u16* __restrict__ Wbase,
    float* __restrict__ Cout) {
    __shared__ __align__(16) u16 As[128 * 32];
    __shared__ __align__(16) u16 Ws[128 * 32];
    const int t = threadIdx.x, l = t & 63, wid = t >> 6;
    const int m0 = blockIdx.y << 7, n0 = blockIdx.x << 7;
    const u16* W2 = Wbase;

    f32x4 acc[4][4];
#pragma unroll
    for (int i = 0; i < 4; ++i)
#pragma unroll
        for (int j = 0; j < 4; ++j) acc[i][j] = (f32x4){0.f, 0.f, 0.f, 0.f};

    int orow[2], ocs[2];
#pragma unroll
    for (int p = 0; p < 2; ++p) {
        int o = wid * 1024 + l * 16 + p * 4096;
        orow[p] = o >> 6;
        ocs[p] = ((o >> 4) & 3) ^ ((o >> 6) & 3);
    }
    const int wr = (wid >> 1) << 6, wc = (wid & 1) << 6;

    for (int k0 = 0; k0 < 3072; k0 += 32) {
        const int rg3 = k0 >> 10, kb = k0 & 1023;
        const int ka = (rg3 == 1 ? 1024 : 0) + kb;
        const int kw = (rg3 == 0 ? 1024 : 0) + kb;
        __syncthreads();
#pragma unroll
        for (int p = 0; p < 2; ++p) {
            gl2lds16(A2 + (size_t)(m0 + orow[p]) * 2048 + ka + ocs[p] * 8,
                     (u16*)As + (wid * 512 + p * 2048));
            gl2lds16(W2 + (size_t)(n0 + orow[p]) * 2048 + kw + ocs[p] * 8,
                     (u16*)Ws + (wid * 512 + p * 2048));
        }
        __syncthreads();
        bf16x8 af[4], bfr[4];
#pragma unroll
        for (int f = 0; f < 4; ++f) {
            int row = wr + (f << 4) + (l & 15);
            int ch = (l >> 4) ^ (row & 3);
            af[f] = *(const bf16x8*)&As[(row << 5) + (ch << 3)];
            int rown = wc + (f << 4) + (l & 15);
            int chn = (l >> 4) ^ (rown & 3);
            bfr[f] = *(const bf16x8*)&Ws[(rown << 5) + (chn << 3)];
        }
#pragma unroll
        for (int fm = 0; fm < 4; ++fm)
#pragma unroll
            for (int fn = 0; fn < 4; ++fn)
                acc[fm][fn] = mfma16(af[fm], bfr[fn], acc[fm][fn]);
    }

#pragma unroll
    for (int fm = 0; fm < 4; ++fm)
#pragma unroll
        for (int fn = 0; fn < 4; ++fn)
#pragma unroll
            for (int rg = 0; rg < 4; ++rg) {
                int gm = m0 + wr + (fm << 4) + ((l >> 4) << 2) + rg;
                int gn = n0 + wc + (fn << 4) + (l & 15);
                Cout[(size_t)gm * 1024 + gn] = acc[fm][fn][rg];
            }
}

// ---------------------------------------------------------------------------
// V transpose (hi only): [B][H][L][64] -> [B][H][64][L].
// ---------------------------------------------------------------------------
__global__ __launch_bounds__(128) void vtrans(const u16* __restrict__ Vh,
                                              u16* __restrict__ Vth) {
    const int t = threadIdx.x;
    const int kt = (blockIdx.x << 1) + (t >> 6);
    const int h = blockIdx.y, b = blockIdx.z;
    const size_t base = ((size_t)(b * 16 + h)) * 131072;
    const int kv0 = kt << 6;
    const int st = t & 63;
    const int r0 = (st >> 3) << 3;
    const int c0 = (st & 7) << 3;
    ushort4 inv[8][2];
#pragma unroll
    for (int j = 0; j < 8; ++j) {
        const u16* p = Vh + base + (size_t)(kv0 + r0 + j) * 64 + c0;
        inv[j][0] = *(const ushort4*)p;
        inv[j][1] = *(const ushort4*)(p + 4);
    }
#pragma unroll
    for (int i = 0; i < 8; ++i) {
        u16 o[8];
#pragma unroll
        for (int j = 0; j < 8; ++j) {
            ushort4 vv = inv[j][i >> 2];
            const int ii = i & 3;
            o[j] = (ii == 0) ? vv.x : (ii == 1) ? vv.y : (ii == 2) ? vv.z : vv.w;
        }
        u16* q = Vth + base + (size_t)(c0 + i) * 2048 + kv0 + r0;
        *(ushort4*)q = make_ushort4(o[0], o[1], o[2], o[3]);
        *(ushort4*)(q + 4) = make_ushort4(o[4], o[5], o[6], o[7]);
    }
}

// ---------------------------------------------------------------------------
// MFMA flash attention (R7 best: R4 pairing, V hi-only, defer-max,
// truncating P->bf16, setprio). 512 thr / 8 waves; 256 blocks; 64 KB LDS.
// ---------------------------------------------------------------------------
struct QTileState {
    bf16x8 qhf[2], qlf[2];
    f32x4 oacc[4];
    float mrow[4], lrow[4];
};

__device__ __forceinline__ void qstate_init(
    QTileState& st, const u16* Qh, const u16* Ql, size_t hb, int q0, int w, int l) {
    const int rowq = q0 + (w << 4) + (l & 15);
#pragma unroll
    for (int kc = 0; kc < 2; ++kc) {
        const size_t off = hb + (size_t)rowq * 64 + (((kc << 2) + (l >> 4)) << 3);
        st.qhf[kc] = *(const bf16x8*)(Qh + off);
        st.qlf[kc] = *(const bf16x8*)(Ql + off);
    }
#pragma unroll
    for (int i = 0; i < 4; ++i) {
        st.oacc[i] = (f32x4){0.f, 0.f, 0.f, 0.f};
        st.mrow[i] = -INFINITY;
        st.lrow[i] = 0.f;
    }
}

__device__ __forceinline__ void fa_compute(
    QTileState& st, const u16* bKh, const u16* bKl,
    const u16* bVh, int kv0, int q0, int w, int l, u16* Pw) {
    if (kv0 > q0 + (w << 4) + 15) return;

    f32x4 sacc[4];
#pragma unroll
    for (int nf = 0; nf < 4; ++nf) sacc[nf] = (f32x4){0.f, 0.f, 0.f, 0.f};
#pragma unroll
    for (int kc = 0; kc < 2; ++kc) {
        bf16x8 kh_[4], kl_[4];
#pragma unroll
        for (int nf = 0; nf < 4; ++nf) {
            const int row = (nf << 4) + (l & 15);
            const int ch = ((kc << 2) + (l >> 4)) ^ (row & 7);
            kh_[nf] = *(const bf16x8*)&bKh[(row << 6) + (ch << 3)];
            kl_[nf] = *(const bf16x8*)&bKl[(row << 6) + (ch << 3)];
        }
        __builtin_amdgcn_s_setprio(1);
#pragma unroll
        for (int nf = 0; nf < 4; ++nf) {
            sacc[nf] = mfma16(st.qhf[kc], kl_[nf], sacc[nf]);
            sacc[nf] = mfma16(st.qlf[kc], kh_[nf], sacc[nf]);
            sacc[nf] = mfma16(st.qhf[kc], kh_[nf], sacc[nf]);
        }
        __builtin_amdgcn_s_setprio(0);
    }

    const bool domask = (kv0 + 63) > (q0 + (w << 4));
    float pm[4] = {-INFINITY, -INFINITY, -INFINITY, -INFINITY};
    float sv[4][4];
#pragma unroll
    for (int nf = 0; nf < 4; ++nf)
#pragma unroll
        for (int rg = 0; rg < 4; ++rg) {
            float x = sacc[nf][rg];
            if (domask) {
                const int colg = kv0 + (nf << 4) + (l & 15);
                const int rowg = q0 + (w << 4) + ((l >> 4) << 2) + rg;
                if (colg > rowg) x = -INFINITY;
            }
            sv[nf][rg] = x;
            pm[rg] = fmaxf(pm[rg], x);
        }
#pragma unroll
    for (int rg = 0; rg < 4; ++rg) {
        float v = pm[rg];
        v = fmaxf(v, __shfl_xor(v, 1));
        v = fmaxf(v, __shfl_xor(v, 2));
        v = fmaxf(v, __shfl_xor(v, 4));
        v = fmaxf(v, __shfl_xor(v, 8));
        pm[rg] = v;
    }
    const float need = fmaxf(fmaxf(pm[0] - st.mrow[0], pm[1] - st.mrow[1]),
                             fmaxf(pm[2] - st.mrow[2], pm[3] - st.mrow[3]));
    if (__any(need > 8.0f)) {
#pragma unroll
        for (int rg = 0; rg < 4; ++rg) {
            const float mn = fmaxf(st.mrow[rg], pm[rg]);
            const float al = __expf(st.mrow[rg] - mn);
            st.mrow[rg] = mn;
            st.lrow[rg] *= al;
#pragma unroll
            for (int nf = 0; nf < 4; ++nf) st.oacc[nf][rg] *= al;
        }
    }
    float ps[4] = {0.f, 0.f, 0.f, 0.f};
    u16 pb[4][4];
#pragma unroll
    for (int nf = 0; nf < 4; ++nf)
#pragma unroll
        for (int rg = 0; rg < 4; ++rg) {
            const float p = __expf(sv[nf][rg] - st.mrow[rg]);
            ps[rg] += p;
            pb[nf][rg] = f2bf_t(p);
        }
#pragma unroll
    for (int rg = 0; rg < 4; ++rg) {
        float v = ps[rg];
        v += __shfl_xor(v, 1);
        v += __shfl_xor(v, 2);
        v += __shfl_xor(v, 4);
        v += __shfl_xor(v, 8);
        st.lrow[rg] += v;
    }

#pragma unroll
    for (int nf = 0; nf < 4; ++nf)
#pragma unroll
        for (int rg = 0; rg < 4; ++rg) {
            const int r = ((l >> 4) << 2) + rg;
            const int c = (nf << 4) + (l & 15);
            const int ch = (c >> 3) ^ (r & 7);
            Pw[(r << 6) + (ch << 3) + (c & 7)] = pb[nf][rg];
        }
#pragma unroll
    for (int kc = 0; kc < 2; ++kc) {
        const int r = l & 15;
        const int chp = ((kc << 2) + (l >> 4)) ^ (r & 7);
        const bf16x8 pa = *(const bf16x8*)&Pw[(r << 6) + (chp << 3)];
        bf16x8 vh_[4];
#pragma unroll
        for (int nf = 0; nf < 4; ++nf) {
            const int row = (nf << 4) + (l & 15);
            const int cv = ((kc << 2) + (l >> 4)) ^ (row & 7);
            vh_[nf] = *(const bf16x8*)&bVh[(row << 6) + (cv << 3)];
        }
        __builtin_amdgcn_s_setprio(1);
#pragma unroll
        for (int nf = 0; nf < 4; ++nf)
            st.oacc[nf] = mfma16(pa, vh_[nf], st.oacc[nf]);
        __builtin_amdgcn_s_setprio(0);
    }
}

__device__ __forceinline__ void fa_epilogue(
    QTileState& st, u16* A2, int g, int q0, int w, int l) {
    const int b = g >> 4, h = g & 15;
    float inv[4];
#pragma unroll
    for (int rg = 0; rg < 4; ++rg) inv[rg] = 1.0f / st.lrow[rg];
#pragma unroll
    for (int nf = 0; nf < 4; ++nf)
#pragma unroll
        for (int rg = 0; rg < 4; ++rg) {
            const int rowq = q0 + (w << 4) + ((l >> 4) << 2) + rg;
            const int m = (b << 11) + rowq;
            const int d = (nf << 4) + (l & 15);
            const float v = st.oacc[nf][rg] * inv[rg];
            const u16 hi = f2bf(v);
            const u16 lo = f2bf(v - bf2f(hi));
            const size_t rb = (size_t)m * 2048;
            A2[rb + h * 64 + d] = hi;
            A2[rb + 1024 + h * 64 + d] = lo;
        }
}

__global__ __launch_bounds__(512) void flash_mfma(
    const u16* __restrict__ Qh, const u16* __restrict__ Ql,
    const u16* __restrict__ Kh, const u16* __restrict__ Kl,
    const u16* __restrict__ Vth,
    u16* __restrict__ A2) {
    extern __shared__ __align__(16) u16 smem[];
    u16* const KhsA = smem;
    u16* const KlsA = smem + 4096;
    u16* const VhsA = smem + 8192;
    u16* const KhsB = smem + 12288;
    u16* const KlsB = smem + 16384;
    u16* const VhsB = smem + 20480;
    u16* const Ps   = smem + 24576;

    const int t = threadIdx.x, l = t & 63, w = t >> 6;
    const int id = blockIdx.x;
    const int nid = ((id & 7) << 5) + (id >> 3);
    const int g = nid >> 3;
    const int p = nid & 7;
    const int q0A = p << 7;
    const int q0B = (15 - p) << 7;
    const size_t hb = (size_t)g * 131072;

    QTileState stA, stB;
    qstate_init(stA, Qh, Ql, hb, q0A, w, l);
    qstate_init(stB, Qh, Ql, hb, q0B, w, l);

    const int row_s = t >> 3;
    const int cs_s = (t & 7) ^ (row_s & 7);

    auto stage = [&](u16* dKh, u16* dKl, u16* dVh, int kt_) {
        const int kv0s = kt_ << 6;
        const size_t koff = hb + (size_t)(kv0s + row_s) * 64 + cs_s * 8;
        gl2lds16(Kh + koff, dKh + t * 8);
        gl2lds16(Kl + koff, dKl + t * 8);
        const size_t voff = hb + (size_t)row_s * 2048 + kv0s + cs_s * 8;
        gl2lds16(Vth + voff, dVh + t * 8);
    };

    u16* const Pw = Ps + (w << 10);
    const int ntA = (p << 1) + 2;
    const int ntB = 32 - (p << 1);

    stage(KhsA, KlsA, VhsA, 0);
    __syncthreads();
    for (int kt = 0; kt < ntB; kt += 2) {
        stage(KhsB, KlsB, VhsB, kt + 1);
        fa_compute(stB, KhsA, KlsA, VhsA, kt << 6, q0B, w, l, Pw);
        if (kt < ntA)
            fa_compute(stA, KhsA, KlsA, VhsA, kt << 6, q0A, w, l, Pw);
        __syncthreads();
        if (kt + 2 < ntB) stage(KhsA, KlsA, VhsA, kt + 2);
        fa_compute(stB, KhsB, KlsB, VhsB, (kt + 1) << 6, q0B, w, l, Pw);
        if (kt + 1 < ntA)
            fa_compute(stA, KhsB, KlsB, VhsB, (kt + 1) << 6, q0A, w, l, Pw);
        __syncthreads();
    }

    fa_epilogue(stA, A2, g, q0A, w, l);
    fa_epilogue(stB, A2, g, q0B, w, l);
}

// ===========================================================================
// Fallback fp32 path
// ===========================================================================
__global__ __launch_bounds__(256) void gemm_bt_f32(
    const float* __restrict__ A, const float* __restrict__ W,
    float* __restrict__ C, int M, int N, int K) {
    __shared__ float As[16][68];
    __shared__ float Bs[16][68];
    const int t = threadIdx.x;
    const int tx = t & 15, ty = t >> 4;
    const int m0 = blockIdx.y << 6, n0 = blockIdx.x << 6;
    const int lr = t >> 2, lc = (t & 3) << 2;
    const float* Ag = A + (size_t)(m0 + lr) * K + lc;
    const float* Wg = W + (size_t)(n0 + lr) * K + lc;
    float acc[4][4];
#pragma unroll
    for (int i = 0; i < 4; ++i)
#pragma unroll
        for (int j = 0; j < 4; ++j) acc[i][j] = 0.f;
    for (int k0 = 0; k0 < K; k0 += 16) {
        const float4 av = *(const float4*)(Ag + k0);
        const float4 wv = *(const float4*)(Wg + k0);
        __syncthreads();
        As[lc + 0][lr] = av.x; As[lc + 1][lr] = av.y;
        As[lc + 2][lr] = av.z; As[lc + 3][lr] = av.w;
        Bs[lc + 0][lr] = wv.x; Bs[lc + 1][lr] = wv.y;
        Bs[lc + 2][lr] = wv.z; Bs[lc + 3][lr] = wv.w;
        __syncthreads();
#pragma unroll
        for (int kk = 0; kk < 16; ++kk) {
            const float4 a = *(const float4*)&As[kk][ty << 2];
            const float4 b = *(const float4*)&Bs[kk][tx << 2];
            acc[0][0] += a.x * b.x; acc[0][1] += a.x * b.y; acc[0][2] += a.x * b.z; acc[0][3] += a.x * b.w;
            acc[1][0] += a.y * b.x; acc[1][1] += a.y * b.y; acc[1][2] += a.y * b.z; acc[1][3] += a.y * b.w;
            acc[2][0] += a.z * b.x; acc[2][1] += a.z * b.y; acc[2][2] += a.z * b.z; acc[2][3] += a.z * b.w;
            acc[3][0] += a.w * b.x; acc[3][1] += a.w * b.y; acc[3][2] += a.w * b.z; acc[3][3] += a.w * b.w;
        }
    }
#pragma unroll
    for (int i = 0; i < 4; ++i) {
        float4 o;
        o.x = acc[i][0]; o.y = acc[i][1]; o.z = acc[i][2]; o.w = acc[i][3];
        *(float4*)&C[(size_t)(m0 + (ty << 2) + i) * N + n0 + (tx << 2)] = o;
    }
}

#define SW(row, seg) ((((seg) ^ (((row) + ((row) >> 4)) & 15)) << 2))

__global__ __launch_bounds__(256) void flash_f32(
    const float* __restrict__ Q, const float* __restrict__ K,
    const float* __restrict__ V, float* __restrict__ O) {
    __shared__ float Qs[64 * 64];
    __shared__ float KPs[64 * 64];
    __shared__ float Vs[64 * 64];
    const int t = threadIdx.x;
    const int tx = t & 15, ty = t >> 4;
    const int qt = blockIdx.x, h = blockIdx.y, b = blockIdx.z;
    const int q0 = qt << 6;
    const size_t hbase = (size_t)b * L_SEQ * D_MODEL + (size_t)h * D_HEAD;
#pragma unroll
    for (int i = 0; i < 4; ++i) {
        const int idx = t + (i << 8);
        const int rr = idx >> 4, seg = idx & 15;
        const float4 qv = *(const float4*)&Q[hbase + (size_t)(q0 + rr) * D_MODEL + (seg << 2)];
        *(float4*)&Qs[rr * 64 + SW(rr, seg)] = qv;
    }
    float m[4], lr_[4], oacc[4][4];
#pragma unroll
    for (int i = 0; i < 4; ++i) {
        m[i] = -INFINITY; lr_[i] = 0.f;
#pragma unroll
        for (int j = 0; j < 4; ++j) oacc[i][j] = 0.f;
    }
    const int ntile = qt + 1;
    for (int kt = 0; kt < ntile; ++kt) {
        const int kv0 = kt << 6;
        __syncthreads();
#pragma unroll
        for (int i = 0; i < 4; ++i) {
            const int idx = t + (i << 8);
            const int rr = idx >> 4, seg = idx & 15;
            const float4 kv = *(const float4*)&K[hbase + (size_t)(kv0 + rr) * D_MODEL + (seg << 2)];
            const float4 vv = *(const float4*)&V[hbase + (size_t)(kv0 + rr) * D_MODEL + (seg << 2)];
            *(float4*)&KPs[rr * 64 + SW(rr, seg)] = kv;
            *(float4*)&Vs[rr * 64 + SW(rr, seg)] = vv;
        }
        __syncthreads();
        float s[4][4];
#pragma unroll
        for (int i = 0; i < 4; ++i)
#pragma unroll
            for (int j = 0; j < 4; ++j) s[i][j] = 0.f;
#pragma unroll
        for (int seg = 0; seg < 16; ++seg) {
            float4 qv[4], kv[4];
#pragma unroll
            for (int i = 0; i < 4; ++i) {
                const int R = (ty << 2) + i;
                qv[i] = *(const float4*)&Qs[R * 64 + SW(R, seg)];
            }
#pragma unroll
            for (int j = 0; j < 4; ++j) {
                const int Cc = (tx << 2) + j;
                kv[j] = *(const float4*)&KPs[Cc * 64 + SW(Cc, seg)];
            }
#pragma unroll
            for (int i = 0; i < 4; ++i)
#pragma unroll
                for (int j = 0; j < 4; ++j)
                    s[i][j] += qv[i].x * kv[j].x + qv[i].y * kv[j].y +
                               qv[i].z * kv[j].z + qv[i].w * kv[j].w;
        }
        const bool diag = (kt == qt);
        float tm[4];
#pragma unroll
        for (int i = 0; i < 4; ++i) {
            tm[i] = -INFINITY;
#pragma unroll
            for (int j = 0; j < 4; ++j) {
                float sval = s[i][j] * 0.125f;
                if (diag) {
                    const int Cg = kv0 + (tx << 2) + j;
                    const int Rg = q0 + (ty << 2) + i;
                    if (Cg > Rg) sval = -INFINITY;
                }
                s[i][j] = sval;
                tm[i] = fmaxf(tm[i], sval);
            }
            tm[i] = fmaxf(tm[i], __shfl_xor(tm[i], 1));
            tm[i] = fmaxf(tm[i], __shfl_xor(tm[i], 2));
            tm[i] = fmaxf(tm[i], __shfl_xor(tm[i], 4));
            tm[i] = fmaxf(tm[i], __shfl_xor(tm[i], 8));
        }
        float p[4][4];
#pragma unroll
        for (int i = 0; i < 4; ++i) {
            const float mn = fmaxf(m[i], tm[i]);
            const float alpha = __expf(m[i] - mn);
            m[i] = mn;
            float psum = 0.f;
#pragma unroll
            for (int j = 0; j < 4; ++j) {
                p[i][j] = __expf(s[i][j] - mn);
                psum += p[i][j];
            }
            psum += __shfl_xor(psum, 1);
            psum += __shfl_xor(psum, 2);
            psum += __shfl_xor(psum, 4);
            psum += __shfl_xor(psum, 8);
            lr_[i] = lr_[i] * alpha + psum;
#pragma unroll
            for (int j = 0; j < 4; ++j) oacc[i][j] *= alpha;
        }
        __syncthreads();
#pragma unroll
        for (int i = 0; i < 4; ++i) {
            const int R = (ty << 2) + i;
            float4 pv;
            pv.x = p[i][0]; pv.y = p[i][1]; pv.z = p[i][2]; pv.w = p[i][3];
            *(float4*)&KPs[R * 64 + SW(R, tx)] = pv;
        }
        __syncthreads();
#pragma unroll
        for (int cs = 0; cs < 16; ++cs) {
            float pc[4][4];
            float4 vr[4];
#pragma unroll
            for (int i = 0; i < 4; ++i) {
                const int R = (ty << 2) + i;
                const float4 pr = *(const float4*)&KPs[R * 64 + SW(R, cs)];
                pc[i][0] = pr.x; pc[i][1] = pr.y; pc[i][2] = pr.z; pc[i][3] = pr.w;
            }
#pragma unroll
            for (int cc = 0; cc < 4; ++cc) {
                const int Cr = (cs << 2) + cc;
                vr[cc] = *(const float4*)&Vs[Cr * 64 + SW(Cr, tx)];
            }
#pragma unroll
            for (int i = 0; i < 4; ++i)
#pragma unroll
                for (int cc = 0; cc < 4; ++cc) {
                    oacc[i][0] += pc[i][cc] * vr[cc].x;
                    oacc[i][1] += pc[i][cc] * vr[cc].y;
                    oacc[i][2] += pc[i][cc] * vr[cc].z;
                    oacc[i][3] += pc[i][cc] * vr[cc].w;
                }
        }
    }
#pragma unroll
    for (int i = 0; i < 4; ++i) {
        const int R = (ty << 2) + i;
        const float invl = 1.0f / lr_[i];
        float4 o;
        o.x = oacc[i][0] * invl; o.y = oacc[i][1] * invl;
        o.z = oacc[i][2] * invl; o.w = oacc[i][3] * invl;
        *(float4*)&O[hbase + (size_t)(q0 + R) * D_MODEL + (tx << 2)] = o;
    }
}

// ---------------------------------------------------------------------------
extern "C" void kernel_launch(void* const* d_in, const int* in_sizes, int n_in,
                              void* d_out, int out_size, void* d_ws, size_t ws_size,
                              hipStream_t stream) {
    const float* x  = (const float*)d_in[0];
    const float* Wq = (const float*)d_in[2];
    const float* Wk = (const float*)d_in[3];
    const float* Wv = (const float*)d_in[4];
    const float* Wo = (const float*)d_in[5];
    float* out = (float*)d_out;

    if (ws_size >= 83886080ull) {
        char* ws = (char*)d_ws;
        u16* x2  = (u16*)(ws);                // 16 MB, reused as A2 after QKV
        u16* Wq2 = (u16*)(ws + 16777216);     // Wq2/Wk2/Wv2/Wo2 contiguous 4MB each
        u16* Wo2 = (u16*)(ws + 29360128);
        u16* Qh  = (u16*)(ws + 33554432);
        u16* Ql  = (u16*)(ws + 41943040);
        u16* Kh  = (u16*)(ws + 50331648);
        u16* Kl  = (u16*)(ws + 58720256);
        u16* Vth = (u16*)(ws + 67108864);
        u16* Vh  = (u16*)d_out;               // scratch, rewritten by final GEMM

        hipFuncSetAttribute((const void*)flash_mfma,
                            hipFuncAttributeMaxDynamicSharedMemorySize, 65536);
        hipFuncSetAttribute((const void*)gemm256_qkv,
                            hipFuncAttributeMaxDynamicSharedMemorySize, 131072);

        split_hl<<<4096, 256, 0, stream>>>(x, x2);
        split_w4<<<dim3(1024, 4), 256, 0, stream>>>(Wq, Wk, Wv, Wo, Wq2);
        gemm256_qkv<<<192, 512, 131072, stream>>>(x2, Wq2, Qh, Ql, Kh, Kl, Vh);
        vtrans<<<dim3(16, 16, 2), 128, 0, stream>>>(Vh, Vth);
        flash_mfma<<<256, 512, 65536, stream>>>(Qh, Ql, Kh, Kl, Vth, x2);
        gemm_ks<0><<<dim3(8, 32), 256, 0, stream>>>(x2, Wo2, out);
    } else {
        const int M = B_SIZE * L_SEQ, N = D_MODEL, Kd = D_MODEL;
        float* Qw = (float*)d_ws;
        float* Kw = Qw + (size_t)M * D_MODEL;
        float* Vw = Kw + (size_t)M * D_MODEL;
        float* Aw = Vw + (size_t)M * D_MODEL;
        dim3 gg(N / 64, M / 64);
        gemm_bt_f32<<<gg, 256, 0, stream>>>(x, Wq, Qw, M, N, Kd);
        gemm_bt_f32<<<gg, 256, 0, stream>>>(x, Wk, Kw, M, N, Kd);
        gemm_bt_f32<<<gg, 256, 0, stream>>>(x, Wv, Vw, M, N, Kd);
        flash_f32<<<dim3(L_SEQ / 64, N_HEAD, B_SIZE), 256, 0, stream>>>(Qw, Kw, Vw, Aw);
        gemm_bt_f32<<<gg, 256, 0, stream>>>(Aw, Wo, out, M, N, Kd);
    }
}

// Round 9
// 244.750 us; speedup vs baseline: 1.0248x; 1.0248x over previous
//
#include <hip/hip_runtime.h>
#include <math.h>

#define L_SEQ  2048
#define D_MODEL 1024
#define N_HEAD 16
#define D_HEAD 64
#define B_SIZE 2

typedef __attribute__((ext_vector_type(8))) short bf16x8;
typedef __attribute__((ext_vector_type(4))) float f32x4;
typedef unsigned short u16;
typedef unsigned int u32;

__device__ __forceinline__ f32x4 mfma16(bf16x8 a, bf16x8 b, f32x4 c) {
    return __builtin_amdgcn_mfma_f32_16x16x32_bf16(a, b, c, 0, 0, 0);
}

__device__ __forceinline__ u16 f2bf(float x) {
    u32 u = __builtin_bit_cast(u32, x);
    u32 r = (u + 0x7FFFu + ((u >> 16) & 1u)) >> 16;
    return (u16)r;
}
__device__ __forceinline__ u16 f2bf_t(float x) {  // truncate (P only)
    return (u16)(__builtin_bit_cast(u32, x) >> 16);
}
__device__ __forceinline__ float bf2f(u16 h) {
    u32 u = ((u32)h) << 16;
    return __builtin_bit_cast(float, u);
}

__device__ __forceinline__ void gl2lds16(const void* g, void* l) {
    __builtin_amdgcn_global_load_lds(
        (__attribute__((address_space(1))) void*)(g),
        (__attribute__((address_space(3))) void*)(l), 16, 0, 0);
}

// ---------------------------------------------------------------------------
// fused split: x (4096 blocks) + 4 weights (4096 blocks) -> [hi|lo] bf16 rows
// ---------------------------------------------------------------------------
__global__ __launch_bounds__(256) void split_all(
    const float* __restrict__ x,
    const float* __restrict__ w0, const float* __restrict__ w1,
    const float* __restrict__ w2, const float* __restrict__ w3,
    u16* __restrict__ x2, u16* __restrict__ wout) {
    const int id = blockIdx.x;
    const float* in;
    u16* out;
    int idx;
    if (id < 4096) {
        in = x; out = x2; idx = id * 256 + threadIdx.x;
    } else {
        const int wi = (id - 4096) >> 10;
        const int blk = (id - 4096) & 1023;
        in = (wi == 0) ? w0 : (wi == 1) ? w1 : (wi == 2) ? w2 : w3;
        out = wout + (size_t)wi * 2097152;
        idx = blk * 256 + threadIdx.x;
    }
    const int c4 = idx << 2;
    const int r = c4 >> 10, c = c4 & 1023;
    float4 v = *(const float4*)(in + c4);
    u16 h0 = f2bf(v.x), h1 = f2bf(v.y), h2 = f2bf(v.z), h3 = f2bf(v.w);
    ushort4 hi = make_ushort4(h0, h1, h2, h3);
    ushort4 lo = make_ushort4(f2bf(v.x - bf2f(h0)), f2bf(v.y - bf2f(h1)),
                              f2bf(v.z - bf2f(h2)), f2bf(v.w - bf2f(h3)));
    *(ushort4*)(out + (size_t)r * 2048 + c) = hi;
    *(ushort4*)(out + (size_t)r * 2048 + 1024 + c) = lo;
}

// ---------------------------------------------------------------------------
// 8-phase 256x256 QKV GEMM (kept from R8 — equal to 2-phase, lower FETCH).
// ---------------------------------------------------------------------------
__device__ __forceinline__ int kaOf(int x) {
    return (((x >> 4) == 1) ? 1024 : 0) + ((x << 6) & 1023);
}
__device__ __forceinline__ int kwOf(int x) {
    return (((x >> 4) == 0) ? 1024 : 0) + ((x << 6) & 1023);
}

#define SBAR()  do { __builtin_amdgcn_sched_barrier(0); \
                     __builtin_amdgcn_s_barrier(); \
                     __builtin_amdgcn_sched_barrier(0); } while (0)

__global__ __launch_bounds__(512) void gemm256_qkv(
    const u16* __restrict__ A2, const u16* __restrict__ Wall,
    u16* __restrict__ Qh, u16* __restrict__ Ql,
    u16* __restrict__ Kh, u16* __restrict__ Kl,
    u16* __restrict__ Vh) {
    extern __shared__ __align__(16) u16 smem[];

    const int t = threadIdx.x, l = t & 63, wid = t >> 6;
    const int id = blockIdx.x;
    const int wg = (id & 7) * 24 + (id >> 3);
    const int mt = wg / 12, ntile = wg % 12;
    const int m0 = mt << 8, n0 = ntile << 8;

    const int wrH = wid >> 2;
    const int wc = (wid & 3) << 6;
    const int bHalf = (wid & 3) >> 1;
    const int brB = (wid & 1) << 6;

    f32x4 acc[8][4];
#pragma unroll
    for (int i = 0; i < 8; ++i)
#pragma unroll
        for (int j = 0; j < 4; ++j) acc[i][j] = (f32x4){0.f, 0.f, 0.f, 0.f};

    const int sr = t >> 3, sc = t & 7;

    auto stageA = [&](int x, int half) {
        const int koff = kaOf(x);
        u16* dst = smem + ((x & 1) * 32768) + half * 8192;
        const u16* srcb = A2 + (size_t)(m0 + half * 128) * 2048 + koff;
#pragma unroll
        for (int p = 0; p < 2; ++p) {
            const int r = sr + p * 64;
            const int ck = sc ^ (r & 7);
            gl2lds16(srcb + (size_t)r * 2048 + ck * 8, dst + (t + p * 512) * 8);
        }
    };
    auto stageB = [&](int x, int half) {
        const int koff = kwOf(x);
        u16* dst = smem + 16384 + ((x & 1) * 32768) + half * 8192;
        const u16* srcb = Wall + (size_t)(n0 + half * 128) * 2048 + koff;
#pragma unroll
        for (int p = 0; p < 2; ++p) {
            const int r = sr + p * 64;
            const int ck = sc ^ (r & 7);
            gl2lds16(srcb + (size_t)r * 2048 + ck * 8, dst + (t + p * 512) * 8);
        }
    };
    auto dsA = [&](int s, int mh, int kc, bf16x8 af[4]) {
        const u16* Ab = smem + s * 32768 + wrH * 8192;
#pragma unroll
        for (int f = 0; f < 4; ++f) {
            const int r = mh * 64 + f * 16 + (l & 15);
            const int c8 = kc * 4 + (l >> 4);
            af[f] = *(const bf16x8*)&Ab[r * 64 + ((c8 ^ (r & 7)) << 3)];
        }
    };
    auto dsB = [&](int s, int kc, bf16x8 bfr[4]) {
        const u16* Bb = smem + 16384 + s * 32768 + bHalf * 8192;
#pragma unroll
        for (int f = 0; f < 4; ++f) {
            const int r = brB + f * 16 + (l & 15);
            const int c8 = kc * 4 + (l >> 4);
            bfr[f] = *(const bf16x8*)&Bb[r * 64 + ((c8 ^ (r & 7)) << 3)];
        }
    };

    stageB(0, 0); stageB(0, 1); stageA(0, 0); stageA(0, 1);
    stageB(1, 0); stageB(1, 1);
    __builtin_amdgcn_sched_barrier(0);
    asm volatile("s_waitcnt vmcnt(4)" ::: "memory");
    __builtin_amdgcn_s_barrier();
    __builtin_amdgcn_sched_barrier(0);

    const int NT = 48;
    bf16x8 breg0[4], breg1[4], af[4];
    for (int tt = 0; tt < NT; ++tt) {
        const int s = tt & 1;
        dsA(s, 0, 0, af); dsB(s, 0, breg0);
        if (tt + 1 < NT) stageA(tt + 1, 0);
        SBAR();
        __builtin_amdgcn_s_setprio(1);
#pragma unroll
        for (int f = 0; f < 4; ++f)
#pragma unroll
            for (int fn = 0; fn < 4; ++fn)
                acc[f][fn] = mfma16(af[f], breg0[fn], acc[f][fn]);
        __builtin_amdgcn_s_setprio(0);
        SBAR();
        dsA(s, 0, 1, af); dsB(s, 1, breg1);
        if (tt + 1 < NT) stageA(tt + 1, 1);
        SBAR();
        __builtin_amdgcn_s_setprio(1);
#pragma unroll
        for (int f = 0; f < 4; ++f)
#pragma unroll
            for (int fn = 0; fn < 4; ++fn)
                acc[f][fn] = mfma16(af[f], breg1[fn], acc[f][fn]);
        __builtin_amdgcn_s_setprio(0);
        SBAR();
        dsA(s, 1, 0, af);
        if (tt + 2 < NT) stageB(tt + 2, 0);
        SBAR();
        __builtin_amdgcn_s_setprio(1);
#pragma unroll
        for (int f = 0; f < 4; ++f)
#pragma unroll
            for (int fn = 0; fn < 4; ++fn)
                acc[4 + f][fn] = mfma16(af[f], breg0[fn], acc[4 + f][fn]);
        __builtin_amdgcn_s_setprio(0);
        SBAR();
        dsA(s, 1, 1, af);
        if (tt + 2 < NT) stageB(tt + 2, 1);
        SBAR();
        __builtin_amdgcn_s_setprio(1);
#pragma unroll
        for (int f = 0; f < 4; ++f)
#pragma unroll
            for (int fn = 0; fn < 4; ++fn)
                acc[4 + f][fn] = mfma16(af[f], breg1[fn], acc[4 + f][fn]);
        __builtin_amdgcn_s_setprio(0);
        __builtin_amdgcn_sched_barrier(0);
        if (tt + 2 < NT) {
            asm volatile("s_waitcnt vmcnt(4)" ::: "memory");
        } else if (tt + 1 < NT) {
            asm volatile("s_waitcnt vmcnt(0)" ::: "memory");
        }
        __builtin_amdgcn_s_barrier();
        __builtin_amdgcn_sched_barrier(0);
    }

#pragma unroll
    for (int fm = 0; fm < 8; ++fm)
#pragma unroll
        for (int fn = 0; fn < 4; ++fn)
#pragma unroll
            for (int rg = 0; rg < 4; ++rg) {
                const int gm = m0 + wrH * 128 + fm * 16 + ((l >> 4) << 2) + rg;
                const int gn = n0 + wc + fn * 16 + (l & 15);
                const int z = gn >> 10, col = gn & 1023;
                float v = acc[fm][fn][rg];
                if (z == 0) v *= 0.125f;
                const int b = gm >> 11, lq = gm & 2047;
                const int h = col >> 6, d = col & 63;
                const size_t oi = (((size_t)(b * 16 + h)) * 2048 + lq) * 64 + d;
                const u16 hi = f2bf(v);
                if (z == 0) { Qh[oi] = hi; Ql[oi] = f2bf(v - bf2f(hi)); }
                else if (z == 1) { Kh[oi] = hi; Kl[oi] = f2bf(v - bf2f(hi)); }
                else { Vh[oi] = hi; }
            }
}

// ---------------------------------------------------------------------------
// Wo GEMM: 128x64 tiles, 512 blocks (2/CU), XCD-chunked. BK=32, bf16x3.
// ---------------------------------------------------------------------------
__global__ __launch_bounds__(256) void gemm_wo(
    const u16* __restrict__ A2, const u16* __restrict__ W2,
    float* __restrict__ Cout) {
    __shared__ __align__(16) u16 As[128 * 32];
    __shared__ __align__(16) u16 Ws2[64 * 32];
    const int t = threadIdx.x, l = t & 63, wid = t >> 6;
    // 512 blocks = 8 XCDs x 64; nid: m-major within XCD chunk
    const int id = blockIdx.x;
    const int nid = ((id & 7) << 6) + (id >> 3);
    const int m0 = (nid >> 4) << 7;   // 32 m-tiles
    const int n0 = (nid & 15) << 6;   // 16 n-tiles
    const int wm = wid >> 1, wn = wid & 1;

    f32x4 acc[4][2];
#pragma unroll
    for (int i = 0; i < 4; ++i)
#pragma unroll
        for (int j = 0; j < 2; ++j) acc[i][j] = (f32x4){0.f, 0.f, 0.f, 0.f};

    const int arow0 = t >> 2, ach0 = (t & 3) ^ (arow0 & 3);
    const int arow1 = (t + 256) >> 2, ach1 = (t & 3) ^ (arow1 & 3);
    const int brow = t >> 2, bch = (t & 3) ^ (brow & 3);

    for (int k0 = 0; k0 < 3072; k0 += 32) {
        const int rg3 = k0 >> 10, kb = k0 & 1023;
        const int ka = (rg3 == 1 ? 1024 : 0) + kb;
        const int kw = (rg3 == 0 ? 1024 : 0) + kb;
        __syncthreads();
        gl2lds16(A2 + (size_t)(m0 + arow0) * 2048 + ka + ach0 * 8,
                 (u16*)As + t * 8);
        gl2lds16(A2 + (size_t)(m0 + arow1) * 2048 + ka + ach1 * 8,
                 (u16*)As + (t + 256) * 8);
        if (t < 256)
            gl2lds16(W2 + (size_t)(n0 + brow) * 2048 + kw + bch * 8,
                     (u16*)Ws2 + t * 8);
        __syncthreads();
        bf16x8 af[4], bfr[2];
#pragma unroll
        for (int f = 0; f < 4; ++f) {
            const int row = wm * 64 + f * 16 + (l & 15);
            const int ch = (l >> 4) ^ (row & 3);
            af[f] = *(const bf16x8*)&As[(row << 5) + (ch << 3)];
        }
#pragma unroll
        for (int f = 0; f < 2; ++f) {
            const int rown = wn * 32 + f * 16 + (l & 15);
            const int chn = (l >> 4) ^ (rown & 3);
            bfr[f] = *(const bf16x8*)&Ws2[(rown << 5) + (chn << 3)];
        }
        __builtin_amdgcn_s_setprio(1);
#pragma unroll
        for (int fm = 0; fm < 4; ++fm)
#pragma unroll
            for (int fn = 0; fn < 2; ++fn)
                acc[fm][fn] = mfma16(af[fm], bfr[fn], acc[fm][fn]);
        __builtin_amdgcn_s_setprio(0);
    }

#pragma unroll
    for (int fm = 0; fm < 4; ++fm)
#pragma unroll
        for (int fn = 0; fn < 2; ++fn)
#pragma unroll
            for (int rg = 0; rg < 4; ++rg) {
                const int gm = m0 + wm * 64 + fm * 16 + ((l >> 4) << 2) + rg;
                const int gn = n0 + wn * 32 + fn * 16 + (l & 15);
                Cout[(size_t)gm * 1024 + gn] = acc[fm][fn][rg];
            }
}

// ---------------------------------------------------------------------------
// V transpose (hi only): [B][H][L][64] -> [B][H][64][L].
// ---------------------------------------------------------------------------
__global__ __launch_bounds__(128) void vtrans(const u16* __restrict__ Vh,
                                              u16* __restrict__ Vth) {
    const int t = threadIdx.x;
    const int kt = (blockIdx.x << 1) + (t >> 6);
    const int h = blockIdx.y, b = blockIdx.z;
    const size_t base = ((size_t)(b * 16 + h)) * 131072;
    const int kv0 = kt << 6;
    const int st = t & 63;
    const int r0 = (st >> 3) << 3;
    const int c0 = (st & 7) << 3;
    ushort4 inv[8][2];
#pragma unroll
    for (int j = 0; j < 8; ++j) {
        const u16* p = Vh + base + (size_t)(kv0 + r0 + j) * 64 + c0;
        inv[j][0] = *(const ushort4*)p;
        inv[j][1] = *(const ushort4*)(p + 4);
    }
#pragma unroll
    for (int i = 0; i < 8; ++i) {
        u16 o[8];
#pragma unroll
        for (int j = 0; j < 8; ++j) {
            ushort4 vv = inv[j][i >> 2];
            const int ii = i & 3;
            o[j] = (ii == 0) ? vv.x : (ii == 1) ? vv.y : (ii == 2) ? vv.z : vv.w;
        }
        u16* q = Vth + base + (size_t)(c0 + i) * 2048 + kv0 + r0;
        *(ushort4*)q = make_ushort4(o[0], o[1], o[2], o[3]);
        *(ushort4*)(q + 4) = make_ushort4(o[4], o[5], o[6], o[7]);
    }
}

// ---------------------------------------------------------------------------
// MFMA flash attention. R7 structure + fused PV (shared V-fragment loads,
// separate P buffers per state). 512 thr / 8 waves; 256 blocks; 80 KB LDS.
// ---------------------------------------------------------------------------
struct QTileState {
    bf16x8 qhf[2], qlf[2];
    f32x4 oacc[4];
    float mrow[4], lrow[4];
};

__device__ __forceinline__ void qstate_init(
    QTileState& st, const u16* Qh, const u16* Ql, size_t hb, int q0, int w, int l) {
    const int rowq = q0 + (w << 4) + (l & 15);
#pragma unroll
    for (int kc = 0; kc < 2; ++kc) {
        const size_t off = hb + (size_t)rowq * 64 + (((kc << 2) + (l >> 4)) << 3);
        st.qhf[kc] = *(const bf16x8*)(Qh + off);
        st.qlf[kc] = *(const bf16x8*)(Ql + off);
    }
#pragma unroll
    for (int i = 0; i < 4; ++i) {
        st.oacc[i] = (f32x4){0.f, 0.f, 0.f, 0.f};
        st.mrow[i] = -INFINITY;
        st.lrow[i] = 0.f;
    }
}

// QK^T 3-product + online softmax; fills pb (bf16 P) and updates st.
__device__ __forceinline__ void fa_qk_softmax(
    QTileState& st, const u16* bKh, const u16* bKl,
    int kv0, int q0, int w, int l, u16 pb[4][4]) {
    f32x4 sacc[4];
#pragma unroll
    for (int nf = 0; nf < 4; ++nf) sacc[nf] = (f32x4){0.f, 0.f, 0.f, 0.f};
#pragma unroll
    for (int kc = 0; kc < 2; ++kc) {
        bf16x8 kh_[4], kl_[4];
#pragma unroll
        for (int nf = 0; nf < 4; ++nf) {
            const int row = (nf << 4) + (l & 15);
            const int ch = ((kc << 2) + (l >> 4)) ^ (row & 7);
            kh_[nf] = *(const bf16x8*)&bKh[(row << 6) + (ch << 3)];
            kl_[nf] = *(const bf16x8*)&bKl[(row << 6) + (ch << 3)];
        }
        __builtin_amdgcn_s_setprio(1);
#pragma unroll
        for (int nf = 0; nf < 4; ++nf) {
            sacc[nf] = mfma16(st.qhf[kc], kl_[nf], sacc[nf]);
            sacc[nf] = mfma16(st.qlf[kc], kh_[nf], sacc[nf]);
            sacc[nf] = mfma16(st.qhf[kc], kh_[nf], sacc[nf]);
        }
        __builtin_amdgcn_s_setprio(0);
    }

    const bool domask = (kv0 + 63) > (q0 + (w << 4));
    float pm[4] = {-INFINITY, -INFINITY, -INFINITY, -INFINITY};
    float sv[4][4];
#pragma unroll
    for (int nf = 0; nf < 4; ++nf)
#pragma unroll
        for (int rg = 0; rg < 4; ++rg) {
            float x = sacc[nf][rg];
            if (domask) {
                const int colg = kv0 + (nf << 4) + (l & 15);
                const int rowg = q0 + (w << 4) + ((l >> 4) << 2) + rg;
                if (colg > rowg) x = -INFINITY;
            }
            sv[nf][rg] = x;
            pm[rg] = fmaxf(pm[rg], x);
        }
#pragma unroll
    for (int rg = 0; rg < 4; ++rg) {
        float v = pm[rg];
        v = fmaxf(v, __shfl_xor(v, 1));
        v = fmaxf(v, __shfl_xor(v, 2));
        v = fmaxf(v, __shfl_xor(v, 4));
        v = fmaxf(v, __shfl_xor(v, 8));
        pm[rg] = v;
    }
    const float need = fmaxf(fmaxf(pm[0] - st.mrow[0], pm[1] - st.mrow[1]),
                             fmaxf(pm[2] - st.mrow[2], pm[3] - st.mrow[3]));
    if (__any(need > 8.0f)) {
#pragma unroll
        for (int rg = 0; rg < 4; ++rg) {
            const float mn = fmaxf(st.mrow[rg], pm[rg]);
            const float al = __expf(st.mrow[rg] - mn);
            st.mrow[rg] = mn;
            st.lrow[rg] *= al;
#pragma unroll
            for (int nf = 0; nf < 4; ++nf) st.oacc[nf][rg] *= al;
        }
    }
    float ps[4] = {0.f, 0.f, 0.f, 0.f};
#pragma unroll
    for (int nf = 0; nf < 4; ++nf)
#pragma unroll
        for (int rg = 0; rg < 4; ++rg) {
            const float p = __expf(sv[nf][rg] - st.mrow[rg]);
            ps[rg] += p;
            pb[nf][rg] = f2bf_t(p);
        }
#pragma unroll
    for (int rg = 0; rg < 4; ++rg) {
        float v = ps[rg];
        v += __shfl_xor(v, 1);
        v += __shfl_xor(v, 2);
        v += __shfl_xor(v, 4);
        v += __shfl_xor(v, 8);
        st.lrow[rg] += v;
    }
}

__device__ __forceinline__ void fa_writeP(const u16 pb[4][4], int l, u16* Pw) {
#pragma unroll
    for (int nf = 0; nf < 4; ++nf)
#pragma unroll
        for (int rg = 0; rg < 4; ++rg) {
            const int r = ((l >> 4) << 2) + rg;
            const int c = (nf << 4) + (l & 15);
            const int ch = (c >> 3) ^ (r & 7);
            Pw[(r << 6) + (ch << 3) + (c & 7)] = pb[nf][rg];
        }
}

__device__ __forceinline__ void fa_epilogue(
    QTileState& st, u16* A2, int g, int q0, int w, int l) {
    const int b = g >> 4, h = g & 15;
    float inv[4];
#pragma unroll
    for (int rg = 0; rg < 4; ++rg) inv[rg] = 1.0f / st.lrow[rg];
#pragma unroll
    for (int nf = 0; nf < 4; ++nf)
#pragma unroll
        for (int rg = 0; rg < 4; ++rg) {
            const int rowq = q0 + (w << 4) + ((l >> 4) << 2) + rg;
            const int m = (b << 11) + rowq;
            const int d = (nf << 4) + (l & 15);
            const float v = st.oacc[nf][rg] * inv[rg];
            const u16 hi = f2bf(v);
            const u16 lo = f2bf(v - bf2f(hi));
            const size_t rb = (size_t)m * 2048;
            A2[rb + h * 64 + d] = hi;
            A2[rb + 1024 + h * 64 + d] = lo;
        }
}

__global__ __launch_bounds__(512) void flash_mfma(
    const u16* __restrict__ Qh, const u16* __restrict__ Ql,
    const u16* __restrict__ Kh, const u16* __restrict__ Kl,
    const u16* __restrict__ Vth,
    u16* __restrict__ A2) {
    extern __shared__ __align__(16) u16 smem[];
    u16* const KhsA = smem;
    u16* const KlsA = smem + 4096;
    u16* const VhsA = smem + 8192;
    u16* const KhsB = smem + 12288;
    u16* const KlsB = smem + 16384;
    u16* const VhsB = smem + 20480;
    u16* const PsB  = smem + 24576;   // 8 waves x 1024
    u16* const PsA  = smem + 32768;   // 8 waves x 1024

    const int t = threadIdx.x, l = t & 63, w = t >> 6;
    const int id = blockIdx.x;
    const int nid = ((id & 7) << 5) + (id >> 3);
    const int g = nid >> 3;
    const int p = nid & 7;
    const int q0A = p << 7;
    const int q0B = (15 - p) << 7;
    const size_t hb = (size_t)g * 131072;

    QTileState stA, stB;
    qstate_init(stA, Qh, Ql, hb, q0A, w, l);
    qstate_init(stB, Qh, Ql, hb, q0B, w, l);

    const int row_s = t >> 3;
    const int cs_s = (t & 7) ^ (row_s & 7);

    auto stage = [&](u16* dKh, u16* dKl, u16* dVh, int kt_) {
        const int kv0s = kt_ << 6;
        const size_t koff = hb + (size_t)(kv0s + row_s) * 64 + cs_s * 8;
        gl2lds16(Kh + koff, dKh + t * 8);
        gl2lds16(Kl + koff, dKl + t * 8);
        const size_t voff = hb + (size_t)row_s * 2048 + kv0s + cs_s * 8;
        gl2lds16(Vth + voff, dVh + t * 8);
    };

    u16* const PwB = PsB + (w << 10);
    u16* const PwA = PsA + (w << 10);
    const int ntA = (p << 1) + 2;
    const int ntB = 32 - (p << 1);

    // one KV-tile compute for both states with shared V-fragment loads
    auto unit = [&](const u16* bKh, const u16* bKl, const u16* bVh, int kt_) {
        const int kv0 = kt_ << 6;
        const bool aB = kv0 <= q0B + (w << 4) + 15;
        const bool aA = (kt_ < ntA) && (kv0 <= q0A + (w << 4) + 15);
        if (!aB && !aA) return;
        u16 pbB[4][4], pbA[4][4];
        if (aB) fa_qk_softmax(stB, bKh, bKl, kv0, q0B, w, l, pbB);
        if (aA) fa_qk_softmax(stA, bKh, bKl, kv0, q0A, w, l, pbA);
        if (aB) fa_writeP(pbB, l, PwB);
        if (aA) fa_writeP(pbA, l, PwA);
#pragma unroll
        for (int kc = 0; kc < 2; ++kc) {
            bf16x8 vh_[4];
#pragma unroll
            for (int nf = 0; nf < 4; ++nf) {
                const int row = (nf << 4) + (l & 15);
                const int cv = ((kc << 2) + (l >> 4)) ^ (row & 7);
                vh_[nf] = *(const bf16x8*)&bVh[(row << 6) + (cv << 3)];
            }
            const int r = l & 15;
            const int chp = ((kc << 2) + (l >> 4)) ^ (r & 7);
            __builtin_amdgcn_s_setprio(1);
            if (aB) {
                const bf16x8 pa = *(const bf16x8*)&PwB[(r << 6) + (chp << 3)];
#pragma unroll
                for (int nf = 0; nf < 4; ++nf)
                    stB.oacc[nf] = mfma16(pa, vh_[nf], stB.oacc[nf]);
            }
            if (aA) {
                const bf16x8 pa = *(const bf16x8*)&PwA[(r << 6) + (chp << 3)];
#pragma unroll
                for (int nf = 0; nf < 4; ++nf)
                    stA.oacc[nf] = mfma16(pa, vh_[nf], stA.oacc[nf]);
            }
            __builtin_amdgcn_s_setprio(0);
        }
    };

    stage(KhsA, KlsA, VhsA, 0);
    __syncthreads();
    for (int kt = 0; kt < ntB; kt += 2) {
        stage(KhsB, KlsB, VhsB, kt + 1);
        unit(KhsA, KlsA, VhsA, kt);
        __syncthreads();
        if (kt + 2 < ntB) stage(KhsA, KlsA, VhsA, kt + 2);
        unit(KhsB, KlsB, VhsB, kt + 1);
        __syncthreads();
    }

    fa_epilogue(stA, A2, g, q0A, w, l);
    fa_epilogue(stB, A2, g, q0B, w, l);
}

// ===========================================================================
// Fallback fp32 path
// ===========================================================================
__global__ __launch_bounds__(256) void gemm_bt_f32(
    const float* __restrict__ A, const float* __restrict__ W,
    float* __restrict__ C, int M, int N, int K) {
    __shared__ float As[16][68];
    __shared__ float Bs[16][68];
    const int t = threadIdx.x;
    const int tx = t & 15, ty = t >> 4;
    const int m0 = blockIdx.y << 6, n0 = blockIdx.x << 6;
    const int lr = t >> 2, lc = (t & 3) << 2;
    const float* Ag = A + (size_t)(m0 + lr) * K + lc;
    const float* Wg = W + (size_t)(n0 + lr) * K + lc;
    float acc[4][4];
#pragma unroll
    for (int i = 0; i < 4; ++i)
#pragma unroll
        for (int j = 0; j < 4; ++j) acc[i][j] = 0.f;
    for (int k0 = 0; k0 < K; k0 += 16) {
        const float4 av = *(const float4*)(Ag + k0);
        const float4 wv = *(const float4*)(Wg + k0);
        __syncthreads();
        As[lc + 0][lr] = av.x; As[lc + 1][lr] = av.y;
        As[lc + 2][lr] = av.z; As[lc + 3][lr] = av.w;
        Bs[lc + 0][lr] = wv.x; Bs[lc + 1][lr] = wv.y;
        Bs[lc + 2][lr] = wv.z; Bs[lc + 3][lr] = wv.w;
        __syncthreads();
#pragma unroll
        for (int kk = 0; kk < 16; ++kk) {
            const float4 a = *(const float4*)&As[kk][ty << 2];
            const float4 b = *(const float4*)&Bs[kk][tx << 2];
            acc[0][0] += a.x * b.x; acc[0][1] += a.x * b.y; acc[0][2] += a.x * b.z; acc[0][3] += a.x * b.w;
            acc[1][0] += a.y * b.x; acc[1][1] += a.y * b.y; acc[1][2] += a.y * b.z; acc[1][3] += a.y * b.w;
            acc[2][0] += a.z * b.x; acc[2][1] += a.z * b.y; acc[2][2] += a.z * b.z; acc[2][3] += a.z * b.w;
            acc[3][0] += a.w * b.x; acc[3][1] += a.w * b.y; acc[3][2] += a.w * b.z; acc[3][3] += a.w * b.w;
        }
    }
#pragma unroll
    for (int i = 0; i < 4; ++i) {
        float4 o;
        o.x = acc[i][0]; o.y = acc[i][1]; o.z = acc[i][2]; o.w = acc[i][3];
        *(float4*)&C[(size_t)(m0 + (ty << 2) + i) * N + n0 + (tx << 2)] = o;
    }
}

#define SW(row, seg) ((((seg) ^ (((row) + ((row) >> 4)) & 15)) << 2))

__global__ __launch_bounds__(256) void flash_f32(
    const float* __restrict__ Q, const float* __restrict__ K,
    const float* __restrict__ V, float* __restrict__ O) {
    __shared__ float Qs[64 * 64];
    __shared__ float KPs[64 * 64];
    __shared__ float Vs[64 * 64];
    const int t = threadIdx.x;
    const int tx = t & 15, ty = t >> 4;
    const int qt = blockIdx.x, h = blockIdx.y, b = blockIdx.z;
    const int q0 = qt << 6;
    const size_t hbase = (size_t)b * L_SEQ * D_MODEL + (size_t)h * D_HEAD;
#pragma unroll
    for (int i = 0; i < 4; ++i) {
        const int idx = t + (i << 8);
        const int rr = idx >> 4, seg = idx & 15;
        const float4 qv = *(const float4*)&Q[hbase + (size_t)(q0 + rr) * D_MODEL + (seg << 2)];
        *(float4*)&Qs[rr * 64 + SW(rr, seg)] = qv;
    }
    float m[4], lr_[4], oacc[4][4];
#pragma unroll
    for (int i = 0; i < 4; ++i) {
        m[i] = -INFINITY; lr_[i] = 0.f;
#pragma unroll
        for (int j = 0; j < 4; ++j) oacc[i][j] = 0.f;
    }
    const int ntile = qt + 1;
    for (int kt = 0; kt < ntile; ++kt) {
        const int kv0 = kt << 6;
        __syncthreads();
#pragma unroll
        for (int i = 0; i < 4; ++i) {
            const int idx = t + (i << 8);
            const int rr = idx >> 4, seg = idx & 15;
            const float4 kv = *(const float4*)&K[hbase + (size_t)(kv0 + rr) * D_MODEL + (seg << 2)];
            const float4 vv = *(const float4*)&V[hbase + (size_t)(kv0 + rr) * D_MODEL + (seg << 2)];
            *(float4*)&KPs[rr * 64 + SW(rr, seg)] = kv;
            *(float4*)&Vs[rr * 64 + SW(rr, seg)] = vv;
        }
        __syncthreads();
        float s[4][4];
#pragma unroll
        for (int i = 0; i < 4; ++i)
#pragma unroll
            for (int j = 0; j < 4; ++j) s[i][j] = 0.f;
#pragma unroll
        for (int seg = 0; seg < 16; ++seg) {
            float4 qv[4], kv[4];
#pragma unroll
            for (int i = 0; i < 4; ++i) {
                const int R = (ty << 2) + i;
                qv[i] = *(const float4*)&Qs[R * 64 + SW(R, seg)];
            }
#pragma unroll
            for (int j = 0; j < 4; ++j) {
                const int Cc = (tx << 2) + j;
                kv[j] = *(const float4*)&KPs[Cc * 64 + SW(Cc, seg)];
            }
#pragma unroll
            for (int i = 0; i < 4; ++i)
#pragma unroll
                for (int j = 0; j < 4; ++j)
                    s[i][j] += qv[i].x * kv[j].x + qv[i].y * kv[j].y +
                               qv[i].z * kv[j].z + qv[i].w * kv[j].w;
        }
        const bool diag = (kt == qt);
        float tm[4];
#pragma unroll
        for (int i = 0; i < 4; ++i) {
            tm[i] = -INFINITY;
#pragma unroll
            for (int j = 0; j < 4; ++j) {
                float sval = s[i][j] * 0.125f;
                if (diag) {
                    const int Cg = kv0 + (tx << 2) + j;
                    const int Rg = q0 + (ty << 2) + i;
                    if (Cg > Rg) sval = -INFINITY;
                }
                s[i][j] = sval;
                tm[i] = fmaxf(tm[i], sval);
            }
            tm[i] = fmaxf(tm[i], __shfl_xor(tm[i], 1));
            tm[i] = fmaxf(tm[i], __shfl_xor(tm[i], 2));
            tm[i] = fmaxf(tm[i], __shfl_xor(tm[i], 4));
            tm[i] = fmaxf(tm[i], __shfl_xor(tm[i], 8));
        }
        float p[4][4];
#pragma unroll
        for (int i = 0; i < 4; ++i) {
            const float mn = fmaxf(m[i], tm[i]);
            const float alpha = __expf(m[i] - mn);
            m[i] = mn;
            float psum = 0.f;
#pragma unroll
            for (int j = 0; j < 4; ++j) {
                p[i][j] = __expf(s[i][j] - mn);
                psum += p[i][j];
            }
            psum += __shfl_xor(psum, 1);
            psum += __shfl_xor(psum, 2);
            psum += __shfl_xor(psum, 4);
            psum += __shfl_xor(psum, 8);
            lr_[i] = lr_[i] * alpha + psum;
#pragma unroll
            for (int j = 0; j < 4; ++j) oacc[i][j] *= alpha;
        }
        __syncthreads();
#pragma unroll
        for (int i = 0; i < 4; ++i) {
            const int R = (ty << 2) + i;
            float4 pv;
            pv.x = p[i][0]; pv.y = p[i][1]; pv.z = p[i][2]; pv.w = p[i][3];
            *(float4*)&KPs[R * 64 + SW(R, tx)] = pv;
        }
        __syncthreads();
#pragma unroll
        for (int cs = 0; cs < 16; ++cs) {
            float pc[4][4];
            float4 vr[4];
#pragma unroll
            for (int i = 0; i < 4; ++i) {
                const int R = (ty << 2) + i;
                const float4 pr = *(const float4*)&KPs[R * 64 + SW(R, cs)];
                pc[i][0] = pr.x; pc[i][1] = pr.y; pc[i][2] = pr.z; pc[i][3] = pr.w;
            }
#pragma unroll
            for (int cc = 0; cc < 4; ++cc) {
                const int Cr = (cs << 2) + cc;
                vr[cc] = *(const float4*)&Vs[Cr * 64 + SW(Cr, tx)];
            }
#pragma unroll
            for (int i = 0; i < 4; ++i)
#pragma unroll
                for (int cc = 0; cc < 4; ++cc) {
                    oacc[i][0] += pc[i][cc] * vr[cc].x;
                    oacc[i][1] += pc[i][cc] * vr[cc].y;
                    oacc[i][2] += pc[i][cc] * vr[cc].z;
                    oacc[i][3] += pc[i][cc] * vr[cc].w;
                }
        }
    }
#pragma unroll
    for (int i = 0; i < 4; ++i) {
        const int R = (ty << 2) + i;
        const float invl = 1.0f / lr_[i];
        float4 o;
        o.x = oacc[i][0] * invl; o.y = oacc[i][1] * invl;
        o.z = oacc[i][2] * invl; o.w = oacc[i][3] * invl;
        *(float4*)&O[hbase + (size_t)(q0 + R) * D_MODEL + (tx << 2)] = o;
    }
}

// ---------------------------------------------------------------------------
extern "C" void kernel_launch(void* const* d_in, const int* in_sizes, int n_in,
                              void* d_out, int out_size, void* d_ws, size_t ws_size,
                              hipStream_t stream) {
    const float* x  = (const float*)d_in[0];
    const float* Wq = (const float*)d_in[2];
    const float* Wk = (const float*)d_in[3];
    const float* Wv = (const float*)d_in[4];
    const float* Wo = (const float*)d_in[5];
    float* out = (float*)d_out;

    if (ws_size >= 83886080ull) {
        char* ws = (char*)d_ws;
        u16* x2  = (u16*)(ws);                // 16 MB, reused as A2 after QKV
        u16* Wq2 = (u16*)(ws + 16777216);     // Wq2/Wk2/Wv2/Wo2 contiguous 4MB each
        u16* Wo2 = (u16*)(ws + 29360128);
        u16* Qh  = (u16*)(ws + 33554432);
        u16* Ql  = (u16*)(ws + 41943040);
        u16* Kh  = (u16*)(ws + 50331648);
        u16* Kl  = (u16*)(ws + 58720256);
        u16* Vth = (u16*)(ws + 67108864);
        u16* Vh  = (u16*)d_out;               // scratch, rewritten by final GEMM

        hipFuncSetAttribute((const void*)flash_mfma,
                            hipFuncAttributeMaxDynamicSharedMemorySize, 81920);
        hipFuncSetAttribute((const void*)gemm256_qkv,
                            hipFuncAttributeMaxDynamicSharedMemorySize, 131072);

        split_all<<<8192, 256, 0, stream>>>(x, Wq, Wk, Wv, Wo, x2, Wq2);
        gemm256_qkv<<<192, 512, 131072, stream>>>(x2, Wq2, Qh, Ql, Kh, Kl, Vh);
        vtrans<<<dim3(16, 16, 2), 128, 0, stream>>>(Vh, Vth);
        flash_mfma<<<256, 512, 81920, stream>>>(Qh, Ql, Kh, Kl, Vth, x2);
        gemm_wo<<<512, 256, 0, stream>>>(x2, Wo2, out);
    } else {
        const int M = B_SIZE * L_SEQ, N = D_MODEL, Kd = D_MODEL;
        float* Qw = (float*)d_ws;
        float* Kw = Qw + (size_t)M * D_MODEL;
        float* Vw = Kw + (size_t)M * D_MODEL;
        float* Aw = Vw + (size_t)M * D_MODEL;
        dim3 gg(N / 64, M / 64);
        gemm_bt_f32<<<gg, 256, 0, stream>>>(x, Wq, Qw, M, N, Kd);
        gemm_bt_f32<<<gg, 256, 0, stream>>>(x, Wk, Kw, M, N, Kd);
        gemm_bt_f32<<<gg, 256, 0, stream>>>(x, Wv, Vw, M, N, Kd);
        flash_f32<<<dim3(L_SEQ / 64, N_HEAD, B_SIZE), 256, 0, stream>>>(Qw, Kw, Vw, Aw);
        gemm_bt_f32<<<gg, 256, 0, stream>>>(Aw, Wo, out, M, N, Kd);
    }
}

// Round 10
// 231.791 us; speedup vs baseline: 1.0821x; 1.0559x over previous
//
#include <hip/hip_runtime.h>
#include <math.h>

#define L_SEQ  2048
#define D_MODEL 1024
#define N_HEAD 16
#define D_HEAD 64
#define B_SIZE 2

typedef __attribute__((ext_vector_type(8))) short bf16x8;
typedef __attribute__((ext_vector_type(4))) float f32x4;
typedef unsigned short u16;
typedef unsigned int u32;

__device__ __forceinline__ f32x4 mfma16(bf16x8 a, bf16x8 b, f32x4 c) {
    return __builtin_amdgcn_mfma_f32_16x16x32_bf16(a, b, c, 0, 0, 0);
}

__device__ __forceinline__ u16 f2bf(float x) {
    u32 u = __builtin_bit_cast(u32, x);
    u32 r = (u + 0x7FFFu + ((u >> 16) & 1u)) >> 16;
    return (u16)r;
}
__device__ __forceinline__ u16 f2bf_t(float x) {  // truncate (P only)
    return (u16)(__builtin_bit_cast(u32, x) >> 16);
}
__device__ __forceinline__ float bf2f(u16 h) {
    u32 u = ((u32)h) << 16;
    return __builtin_bit_cast(float, u);
}

__device__ __forceinline__ void gl2lds16(const void* g, void* l) {
    __builtin_amdgcn_global_load_lds(
        (__attribute__((address_space(1))) void*)(g),
        (__attribute__((address_space(3))) void*)(l), 16, 0, 0);
}

// ---------------------------------------------------------------------------
// fused split: x (4096 blocks) + 4 weights (4096 blocks) -> [hi|lo] bf16 rows
// ---------------------------------------------------------------------------
__global__ __launch_bounds__(256) void split_all(
    const float* __restrict__ x,
    const float* __restrict__ w0, const float* __restrict__ w1,
    const float* __restrict__ w2, const float* __restrict__ w3,
    u16* __restrict__ x2, u16* __restrict__ wout) {
    const int id = blockIdx.x;
    const float* in;
    u16* out;
    int idx;
    if (id < 4096) {
        in = x; out = x2; idx = id * 256 + threadIdx.x;
    } else {
        const int wi = (id - 4096) >> 10;
        const int blk = (id - 4096) & 1023;
        in = (wi == 0) ? w0 : (wi == 1) ? w1 : (wi == 2) ? w2 : w3;
        out = wout + (size_t)wi * 2097152;
        idx = blk * 256 + threadIdx.x;
    }
    const int c4 = idx << 2;
    const int r = c4 >> 10, c = c4 & 1023;
    float4 v = *(const float4*)(in + c4);
    u16 h0 = f2bf(v.x), h1 = f2bf(v.y), h2 = f2bf(v.z), h3 = f2bf(v.w);
    ushort4 hi = make_ushort4(h0, h1, h2, h3);
    ushort4 lo = make_ushort4(f2bf(v.x - bf2f(h0)), f2bf(v.y - bf2f(h1)),
                              f2bf(v.z - bf2f(h2)), f2bf(v.w - bf2f(h3)));
    *(ushort4*)(out + (size_t)r * 2048 + c) = hi;
    *(ushort4*)(out + (size_t)r * 2048 + 1024 + c) = lo;
}

// ---------------------------------------------------------------------------
// 8-phase 256x192 QKV GEMM — 256 blocks = full CU coverage, single round.
// Fused N=3072 (Wq|Wk|Wv stacked), virtual K=3072 (hi/lo region map).
// 512 thr / 8 waves (2M x 4N); per-wave 128x48 out; BK=64; LDS 112 KB.
// A staged as 2 halves (2 loads/thr each), B as 3 thirds (1 load/thr).
// Boundary s_waitcnt vmcnt(3) steady-state — never a drain in main loop.
// ---------------------------------------------------------------------------
__device__ __forceinline__ int kaOf(int x) {
    return (((x >> 4) == 1) ? 1024 : 0) + ((x << 6) & 1023);
}
__device__ __forceinline__ int kwOf(int x) {
    return (((x >> 4) == 0) ? 1024 : 0) + ((x << 6) & 1023);
}

#define SBAR()  do { __builtin_amdgcn_sched_barrier(0); \
                     __builtin_amdgcn_s_barrier(); \
                     __builtin_amdgcn_sched_barrier(0); } while (0)

__global__ __launch_bounds__(512) void gemm256_qkv(
    const u16* __restrict__ A2, const u16* __restrict__ Wall,
    u16* __restrict__ Qh, u16* __restrict__ Ql,
    u16* __restrict__ Kh, u16* __restrict__ Kl,
    u16* __restrict__ Vh) {
    extern __shared__ __align__(16) u16 smem[];
    // layout (u16 idx): A: s*16384 + half*8192 ; B: 32768 + s*12288 + third*4096

    const int t = threadIdx.x, l = t & 63, wid = t >> 6;
    const int id = blockIdx.x;                  // 256 blocks = 8 XCD x 32
    const int wg = (id & 7) * 32 + (id >> 3);   // bijective (256 % 8 == 0)
    const int mt = wg >> 4, ntile = wg & 15;
    const int m0 = mt << 8, n0 = ntile * 192;

    const int wrH = wid >> 2;            // A half (0/1)
    const int wcN = (wid & 3) * 48;      // wave col base within 192

    f32x4 acc[8][3];
#pragma unroll
    for (int i = 0; i < 8; ++i)
#pragma unroll
        for (int j = 0; j < 3; ++j) acc[i][j] = (f32x4){0.f, 0.f, 0.f, 0.f};

    const int sr = t >> 3, sc = t & 7;   // staging row/chunk

    auto stageA = [&](int x, int half) {
        const int koff = kaOf(x);
        u16* dst = smem + (x & 1) * 16384 + half * 8192;
        const u16* srcb = A2 + (size_t)(m0 + half * 128) * 2048 + koff;
#pragma unroll
        for (int p = 0; p < 2; ++p) {
            const int r = sr + p * 64;
            const int ck = sc ^ (r & 7);
            gl2lds16(srcb + (size_t)r * 2048 + ck * 8, dst + t * 8 + p * 4096);
        }
    };
    auto stageB = [&](int x, int third) {
        const int koff = kwOf(x);
        u16* dst = smem + 32768 + (x & 1) * 12288 + third * 4096;
        const int r = sr;                // 0..63 local row in third
        const int ck = sc ^ (r & 7);
        const u16* src = Wall + (size_t)(n0 + third * 64 + r) * 2048 + koff + ck * 8;
        gl2lds16(src, dst + t * 8);
    };
    auto dsA = [&](int s, int mh, int kc, bf16x8 af[4]) {
        const u16* Ab = smem + s * 16384 + wrH * 8192;
#pragma unroll
        for (int f = 0; f < 4; ++f) {
            const int r = mh * 64 + f * 16 + (l & 15);
            const int c8 = kc * 4 + (l >> 4);
            af[f] = *(const bf16x8*)&Ab[r * 64 + ((c8 ^ (r & 7)) << 3)];
        }
    };
    auto dsB = [&](int s, int kc, bf16x8 bfr[3]) {
        const u16* Bb = smem + 32768 + s * 12288;
#pragma unroll
        for (int f = 0; f < 3; ++f) {
            const int row = wcN + f * 16 + (l & 15);
            const int third = row >> 6, lr = row & 63;
            const int c8 = kc * 4 + (l >> 4);
            bfr[f] = *(const bf16x8*)&Bb[third * 4096 + lr * 64 + ((c8 ^ (lr & 7)) << 3)];
        }
    };

    // prologue: B(0) x3, A(0) x4, B(1) x3 -> 10 loads/thread; wait oldest 7
    stageB(0, 0); stageB(0, 1); stageB(0, 2);
    stageA(0, 0); stageA(0, 1);
    stageB(1, 0); stageB(1, 1); stageB(1, 2);
    __builtin_amdgcn_sched_barrier(0);
    asm volatile("s_waitcnt vmcnt(3)" ::: "memory");
    __builtin_amdgcn_s_barrier();
    __builtin_amdgcn_sched_barrier(0);

    const int NT = 48;
    bf16x8 breg0[3], breg1[3], af[4];
    for (int tt = 0; tt < NT; ++tt) {
        const int s = tt & 1;
        // ---- q0: mh0 kc0 (load B kc0); stage A(t+1) h0 ----
        dsA(s, 0, 0, af); dsB(s, 0, breg0);
        if (tt + 1 < NT) stageA(tt + 1, 0);
        SBAR();
        __builtin_amdgcn_s_setprio(1);
#pragma unroll
        for (int f = 0; f < 4; ++f)
#pragma unroll
            for (int fn = 0; fn < 3; ++fn)
                acc[f][fn] = mfma16(af[f], breg0[fn], acc[f][fn]);
        __builtin_amdgcn_s_setprio(0);
        SBAR();
        // ---- q1: mh0 kc1 (load B kc1); stage A(t+1) h1 ----
        dsA(s, 0, 1, af); dsB(s, 1, breg1);
        if (tt + 1 < NT) stageA(tt + 1, 1);
        SBAR();
        __builtin_amdgcn_s_setprio(1);
#pragma unroll
        for (int f = 0; f < 4; ++f)
#pragma unroll
            for (int fn = 0; fn < 3; ++fn)
                acc[f][fn] = mfma16(af[f], breg1[fn], acc[f][fn]);
        __builtin_amdgcn_s_setprio(0);
        SBAR();
        // ---- q2: mh1 kc0 (B from regs); stage B(t+2) thirds 0,1 ----
        dsA(s, 1, 0, af);
        if (tt + 2 < NT) { stageB(tt + 2, 0); stageB(tt + 2, 1); }
        SBAR();
        __builtin_amdgcn_s_setprio(1);
#pragma unroll
        for (int f = 0; f < 4; ++f)
#pragma unroll
            for (int fn = 0; fn < 3; ++fn)
                acc[4 + f][fn] = mfma16(af[f], breg0[fn], acc[4 + f][fn]);
        __builtin_amdgcn_s_setprio(0);
        SBAR();
        // ---- q3: mh1 kc1; stage B(t+2) third 2; boundary counted vmcnt ----
        dsA(s, 1, 1, af);
        if (tt + 2 < NT) stageB(tt + 2, 2);
        SBAR();
        __builtin_amdgcn_s_setprio(1);
#pragma unroll
        for (int f = 0; f < 4; ++f)
#pragma unroll
            for (int fn = 0; fn < 3; ++fn)
                acc[4 + f][fn] = mfma16(af[f], breg1[fn], acc[4 + f][fn]);
        __builtin_amdgcn_s_setprio(0);
        __builtin_amdgcn_sched_barrier(0);
        if (tt + 2 < NT) {
            asm volatile("s_waitcnt vmcnt(3)" ::: "memory");
        } else if (tt + 1 < NT) {
            asm volatile("s_waitcnt vmcnt(0)" ::: "memory");
        }
        __builtin_amdgcn_s_barrier();
        __builtin_amdgcn_sched_barrier(0);
    }

    // ---- epilogue: head-major split bf16 scatter (Q scaled; V hi-only) ----
#pragma unroll
    for (int fm = 0; fm < 8; ++fm)
#pragma unroll
        for (int fn = 0; fn < 3; ++fn)
#pragma unroll
            for (int rg = 0; rg < 4; ++rg) {
                const int gm = m0 + wrH * 128 + fm * 16 + ((l >> 4) << 2) + rg;
                const int gn = n0 + wcN + fn * 16 + (l & 15);
                const int z = gn >> 10, col = gn & 1023;
                float v = acc[fm][fn][rg];
                if (z == 0) v *= 0.125f;  // fold 1/sqrt(dh) into Q
                const int b = gm >> 11, lq = gm & 2047;
                const int h = col >> 6, d = col & 63;
                const size_t oi = (((size_t)(b * 16 + h)) * 2048 + lq) * 64 + d;
                const u16 hi = f2bf(v);
                if (z == 0) { Qh[oi] = hi; Ql[oi] = f2bf(v - bf2f(hi)); }
                else if (z == 1) { Kh[oi] = hi; Kl[oi] = f2bf(v - bf2f(hi)); }
                else { Vh[oi] = hi; }
            }
}

// ---------------------------------------------------------------------------
// Wo GEMM: 128x64 tiles, 512 blocks (2/CU), XCD-chunked. BK=32, bf16x3.
// ---------------------------------------------------------------------------
__global__ __launch_bounds__(256) void gemm_wo(
    const u16* __restrict__ A2, const u16* __restrict__ W2,
    float* __restrict__ Cout) {
    __shared__ __align__(16) u16 As[128 * 32];
    __shared__ __align__(16) u16 Ws2[64 * 32];
    const int t = threadIdx.x, l = t & 63, wid = t >> 6;
    const int id = blockIdx.x;
    const int nid = ((id & 7) << 6) + (id >> 3);
    const int m0 = (nid >> 4) << 7;
    const int n0 = (nid & 15) << 6;
    const int wm = wid >> 1, wn = wid & 1;

    f32x4 acc[4][2];
#pragma unroll
    for (int i = 0; i < 4; ++i)
#pragma unroll
        for (int j = 0; j < 2; ++j) acc[i][j] = (f32x4){0.f, 0.f, 0.f, 0.f};

    const int arow0 = t >> 2, ach0 = (t & 3) ^ (arow0 & 3);
    const int arow1 = (t + 256) >> 2, ach1 = (t & 3) ^ (arow1 & 3);
    const int brow = t >> 2, bch = (t & 3) ^ (brow & 3);

    for (int k0 = 0; k0 < 3072; k0 += 32) {
        const int rg3 = k0 >> 10, kb = k0 & 1023;
        const int ka = (rg3 == 1 ? 1024 : 0) + kb;
        const int kw = (rg3 == 0 ? 1024 : 0) + kb;
        __syncthreads();
        gl2lds16(A2 + (size_t)(m0 + arow0) * 2048 + ka + ach0 * 8,
                 (u16*)As + t * 8);
        gl2lds16(A2 + (size_t)(m0 + arow1) * 2048 + ka + ach1 * 8,
                 (u16*)As + (t + 256) * 8);
        if (t < 256)
            gl2lds16(W2 + (size_t)(n0 + brow) * 2048 + kw + bch * 8,
                     (u16*)Ws2 + t * 8);
        __syncthreads();
        bf16x8 af[4], bfr[2];
#pragma unroll
        for (int f = 0; f < 4; ++f) {
            const int row = wm * 64 + f * 16 + (l & 15);
            const int ch = (l >> 4) ^ (row & 3);
            af[f] = *(const bf16x8*)&As[(row << 5) + (ch << 3)];
        }
#pragma unroll
        for (int f = 0; f < 2; ++f) {
            const int rown = wn * 32 + f * 16 + (l & 15);
            const int chn = (l >> 4) ^ (rown & 3);
            bfr[f] = *(const bf16x8*)&Ws2[(rown << 5) + (chn << 3)];
        }
        __builtin_amdgcn_s_setprio(1);
#pragma unroll
        for (int fm = 0; fm < 4; ++fm)
#pragma unroll
            for (int fn = 0; fn < 2; ++fn)
                acc[fm][fn] = mfma16(af[fm], bfr[fn], acc[fm][fn]);
        __builtin_amdgcn_s_setprio(0);
    }

#pragma unroll
    for (int fm = 0; fm < 4; ++fm)
#pragma unroll
        for (int fn = 0; fn < 2; ++fn)
#pragma unroll
            for (int rg = 0; rg < 4; ++rg) {
                const int gm = m0 + wm * 64 + fm * 16 + ((l >> 4) << 2) + rg;
                const int gn = n0 + wn * 32 + fn * 16 + (l & 15);
                Cout[(size_t)gm * 1024 + gn] = acc[fm][fn][rg];
            }
}

// ---------------------------------------------------------------------------
// V transpose (hi only): [B][H][L][64] -> [B][H][64][L].
// ---------------------------------------------------------------------------
__global__ __launch_bounds__(128) void vtrans(const u16* __restrict__ Vh,
                                              u16* __restrict__ Vth) {
    const int t = threadIdx.x;
    const int kt = (blockIdx.x << 1) + (t >> 6);
    const int h = blockIdx.y, b = blockIdx.z;
    const size_t base = ((size_t)(b * 16 + h)) * 131072;
    const int kv0 = kt << 6;
    const int st = t & 63;
    const int r0 = (st >> 3) << 3;
    const int c0 = (st & 7) << 3;
    ushort4 inv[8][2];
#pragma unroll
    for (int j = 0; j < 8; ++j) {
        const u16* p = Vh + base + (size_t)(kv0 + r0 + j) * 64 + c0;
        inv[j][0] = *(const ushort4*)p;
        inv[j][1] = *(const ushort4*)(p + 4);
    }
#pragma unroll
    for (int i = 0; i < 8; ++i) {
        u16 o[8];
#pragma unroll
        for (int j = 0; j < 8; ++j) {
            ushort4 vv = inv[j][i >> 2];
            const int ii = i & 3;
            o[j] = (ii == 0) ? vv.x : (ii == 1) ? vv.y : (ii == 2) ? vv.z : vv.w;
        }
        u16* q = Vth + base + (size_t)(c0 + i) * 2048 + kv0 + r0;
        *(ushort4*)q = make_ushort4(o[0], o[1], o[2], o[3]);
        *(ushort4*)(q + 4) = make_ushort4(o[4], o[5], o[6], o[7]);
    }
}

// ---------------------------------------------------------------------------
// MFMA flash attention (R9 version: paired tiles, fused PV with shared
// V-fragment loads, V hi-only, defer-max, trunc-P, setprio).
// ---------------------------------------------------------------------------
struct QTileState {
    bf16x8 qhf[2], qlf[2];
    f32x4 oacc[4];
    float mrow[4], lrow[4];
};

__device__ __forceinline__ void qstate_init(
    QTileState& st, const u16* Qh, const u16* Ql, size_t hb, int q0, int w, int l) {
    const int rowq = q0 + (w << 4) + (l & 15);
#pragma unroll
    for (int kc = 0; kc < 2; ++kc) {
        const size_t off = hb + (size_t)rowq * 64 + (((kc << 2) + (l >> 4)) << 3);
        st.qhf[kc] = *(const bf16x8*)(Qh + off);
        st.qlf[kc] = *(const bf16x8*)(Ql + off);
    }
#pragma unroll
    for (int i = 0; i < 4; ++i) {
        st.oacc[i] = (f32x4){0.f, 0.f, 0.f, 0.f};
        st.mrow[i] = -INFINITY;
        st.lrow[i] = 0.f;
    }
}

__device__ __forceinline__ void fa_qk_softmax(
    QTileState& st, const u16* bKh, const u16* bKl,
    int kv0, int q0, int w, int l, u16 pb[4][4]) {
    f32x4 sacc[4];
#pragma unroll
    for (int nf = 0; nf < 4; ++nf) sacc[nf] = (f32x4){0.f, 0.f, 0.f, 0.f};
#pragma unroll
    for (int kc = 0; kc < 2; ++kc) {
        bf16x8 kh_[4], kl_[4];
#pragma unroll
        for (int nf = 0; nf < 4; ++nf) {
            const int row = (nf << 4) + (l & 15);
            const int ch = ((kc << 2) + (l >> 4)) ^ (row & 7);
            kh_[nf] = *(const bf16x8*)&bKh[(row << 6) + (ch << 3)];
            kl_[nf] = *(const bf16x8*)&bKl[(row << 6) + (ch << 3)];
        }
        __builtin_amdgcn_s_setprio(1);
#pragma unroll
        for (int nf = 0; nf < 4; ++nf) {
            sacc[nf] = mfma16(st.qhf[kc], kl_[nf], sacc[nf]);
            sacc[nf] = mfma16(st.qlf[kc], kh_[nf], sacc[nf]);
            sacc[nf] = mfma16(st.qhf[kc], kh_[nf], sacc[nf]);
        }
        __builtin_amdgcn_s_setprio(0);
    }

    const bool domask = (kv0 + 63) > (q0 + (w << 4));
    float pm[4] = {-INFINITY, -INFINITY, -INFINITY, -INFINITY};
    float sv[4][4];
#pragma unroll
    for (int nf = 0; nf < 4; ++nf)
#pragma unroll
        for (int rg = 0; rg < 4; ++rg) {
            float x = sacc[nf][rg];
            if (domask) {
                const int colg = kv0 + (nf << 4) + (l & 15);
                const int rowg = q0 + (w << 4) + ((l >> 4) << 2) + rg;
                if (colg > rowg) x = -INFINITY;
            }
            sv[nf][rg] = x;
            pm[rg] = fmaxf(pm[rg], x);
        }
#pragma unroll
    for (int rg = 0; rg < 4; ++rg) {
        float v = pm[rg];
        v = fmaxf(v, __shfl_xor(v, 1));
        v = fmaxf(v, __shfl_xor(v, 2));
        v = fmaxf(v, __shfl_xor(v, 4));
        v = fmaxf(v, __shfl_xor(v, 8));
        pm[rg] = v;
    }
    const float need = fmaxf(fmaxf(pm[0] - st.mrow[0], pm[1] - st.mrow[1]),
                             fmaxf(pm[2] - st.mrow[2], pm[3] - st.mrow[3]));
    if (__any(need > 8.0f)) {
#pragma unroll
        for (int rg = 0; rg < 4; ++rg) {
            const float mn = fmaxf(st.mrow[rg], pm[rg]);
            const float al = __expf(st.mrow[rg] - mn);
            st.mrow[rg] = mn;
            st.lrow[rg] *= al;
#pragma unroll
            for (int nf = 0; nf < 4; ++nf) st.oacc[nf][rg] *= al;
        }
    }
    float ps[4] = {0.f, 0.f, 0.f, 0.f};
#pragma unroll
    for (int nf = 0; nf < 4; ++nf)
#pragma unroll
        for (int rg = 0; rg < 4; ++rg) {
            const float p = __expf(sv[nf][rg] - st.mrow[rg]);
            ps[rg] += p;
            pb[nf][rg] = f2bf_t(p);
        }
#pragma unroll
    for (int rg = 0; rg < 4; ++rg) {
        float v = ps[rg];
        v += __shfl_xor(v, 1);
        v += __shfl_xor(v, 2);
        v += __shfl_xor(v, 4);
        v += __shfl_xor(v, 8);
        st.lrow[rg] += v;
    }
}

__device__ __forceinline__ void fa_writeP(const u16 pb[4][4], int l, u16* Pw) {
#pragma unroll
    for (int nf = 0; nf < 4; ++nf)
#pragma unroll
        for (int rg = 0; rg < 4; ++rg) {
            const int r = ((l >> 4) << 2) + rg;
            const int c = (nf << 4) + (l & 15);
            const int ch = (c >> 3) ^ (r & 7);
            Pw[(r << 6) + (ch << 3) + (c & 7)] = pb[nf][rg];
        }
}

__device__ __forceinline__ void fa_epilogue(
    QTileState& st, u16* A2, int g, int q0, int w, int l) {
    const int b = g >> 4, h = g & 15;
    float inv[4];
#pragma unroll
    for (int rg = 0; rg < 4; ++rg) inv[rg] = 1.0f / st.lrow[rg];
#pragma unroll
    for (int nf = 0; nf < 4; ++nf)
#pragma unroll
        for (int rg = 0; rg < 4; ++rg) {
            const int rowq = q0 + (w << 4) + ((l >> 4) << 2) + rg;
            const int m = (b << 11) + rowq;
            const int d = (nf << 4) + (l & 15);
            const float v = st.oacc[nf][rg] * inv[rg];
            const u16 hi = f2bf(v);
            const u16 lo = f2bf(v - bf2f(hi));
            const size_t rb = (size_t)m * 2048;
            A2[rb + h * 64 + d] = hi;
            A2[rb + 1024 + h * 64 + d] = lo;
        }
}

__global__ __launch_bounds__(512) void flash_mfma(
    const u16* __restrict__ Qh, const u16* __restrict__ Ql,
    const u16* __restrict__ Kh, const u16* __restrict__ Kl,
    const u16* __restrict__ Vth,
    u16* __restrict__ A2) {
    extern __shared__ __align__(16) u16 smem[];
    u16* const KhsA = smem;
    u16* const KlsA = smem + 4096;
    u16* const VhsA = smem + 8192;
    u16* const KhsB = smem + 12288;
    u16* const KlsB = smem + 16384;
    u16* const VhsB = smem + 20480;
    u16* const PsB  = smem + 24576;
    u16* const PsA  = smem + 32768;

    const int t = threadIdx.x, l = t & 63, w = t >> 6;
    const int id = blockIdx.x;
    const int nid = ((id & 7) << 5) + (id >> 3);
    const int g = nid >> 3;
    const int p = nid & 7;
    const int q0A = p << 7;
    const int q0B = (15 - p) << 7;
    const size_t hb = (size_t)g * 131072;

    QTileState stA, stB;
    qstate_init(stA, Qh, Ql, hb, q0A, w, l);
    qstate_init(stB, Qh, Ql, hb, q0B, w, l);

    const int row_s = t >> 3;
    const int cs_s = (t & 7) ^ (row_s & 7);

    auto stage = [&](u16* dKh, u16* dKl, u16* dVh, int kt_) {
        const int kv0s = kt_ << 6;
        const size_t koff = hb + (size_t)(kv0s + row_s) * 64 + cs_s * 8;
        gl2lds16(Kh + koff, dKh + t * 8);
        gl2lds16(Kl + koff, dKl + t * 8);
        const size_t voff = hb + (size_t)row_s * 2048 + kv0s + cs_s * 8;
        gl2lds16(Vth + voff, dVh + t * 8);
    };

    u16* const PwB = PsB + (w << 10);
    u16* const PwA = PsA + (w << 10);
    const int ntA = (p << 1) + 2;
    const int ntB = 32 - (p << 1);

    auto unit = [&](const u16* bKh, const u16* bKl, const u16* bVh, int kt_) {
        const int kv0 = kt_ << 6;
        const bool aB = kv0 <= q0B + (w << 4) + 15;
        const bool aA = (kt_ < ntA) && (kv0 <= q0A + (w << 4) + 15);
        if (!aB && !aA) return;
        u16 pbB[4][4], pbA[4][4];
        if (aB) fa_qk_softmax(stB, bKh, bKl, kv0, q0B, w, l, pbB);
        if (aA) fa_qk_softmax(stA, bKh, bKl, kv0, q0A, w, l, pbA);
        if (aB) fa_writeP(pbB, l, PwB);
        if (aA) fa_writeP(pbA, l, PwA);
#pragma unroll
        for (int kc = 0; kc < 2; ++kc) {
            bf16x8 vh_[4];
#pragma unroll
            for (int nf = 0; nf < 4; ++nf) {
                const int row = (nf << 4) + (l & 15);
                const int cv = ((kc << 2) + (l >> 4)) ^ (row & 7);
                vh_[nf] = *(const bf16x8*)&bVh[(row << 6) + (cv << 3)];
            }
            const int r = l & 15;
            const int chp = ((kc << 2) + (l >> 4)) ^ (r & 7);
            __builtin_amdgcn_s_setprio(1);
            if (aB) {
                const bf16x8 pa = *(const bf16x8*)&PwB[(r << 6) + (chp << 3)];
#pragma unroll
                for (int nf = 0; nf < 4; ++nf)
                    stB.oacc[nf] = mfma16(pa, vh_[nf], stB.oacc[nf]);
            }
            if (aA) {
                const bf16x8 pa = *(const bf16x8*)&PwA[(r << 6) + (chp << 3)];
#pragma unroll
                for (int nf = 0; nf < 4; ++nf)
                    stA.oacc[nf] = mfma16(pa, vh_[nf], stA.oacc[nf]);
            }
            __builtin_amdgcn_s_setprio(0);
        }
    };

    stage(KhsA, KlsA, VhsA, 0);
    __syncthreads();
    for (int kt = 0; kt < ntB; kt += 2) {
        stage(KhsB, KlsB, VhsB, kt + 1);
        unit(KhsA, KlsA, VhsA, kt);
        __syncthreads();
        if (kt + 2 < ntB) stage(KhsA, KlsA, VhsA, kt + 2);
        unit(KhsB, KlsB, VhsB, kt + 1);
        __syncthreads();
    }

    fa_epilogue(stA, A2, g, q0A, w, l);
    fa_epilogue(stB, A2, g, q0B, w, l);
}

// ===========================================================================
// Fallback fp32 path
// ===========================================================================
__global__ __launch_bounds__(256) void gemm_bt_f32(
    const float* __restrict__ A, const float* __restrict__ W,
    float* __restrict__ C, int M, int N, int K) {
    __shared__ float As[16][68];
    __shared__ float Bs[16][68];
    const int t = threadIdx.x;
    const int tx = t & 15, ty = t >> 4;
    const int m0 = blockIdx.y << 6, n0 = blockIdx.x << 6;
    const int lr = t >> 2, lc = (t & 3) << 2;
    const float* Ag = A + (size_t)(m0 + lr) * K + lc;
    const float* Wg = W + (size_t)(n0 + lr) * K + lc;
    float acc[4][4];
#pragma unroll
    for (int i = 0; i < 4; ++i)
#pragma unroll
        for (int j = 0; j < 4; ++j) acc[i][j] = 0.f;
    for (int k0 = 0; k0 < K; k0 += 16) {
        const float4 av = *(const float4*)(Ag + k0);
        const float4 wv = *(const float4*)(Wg + k0);
        __syncthreads();
        As[lc + 0][lr] = av.x; As[lc + 1][lr] = av.y;
        As[lc + 2][lr] = av.z; As[lc + 3][lr] = av.w;
        Bs[lc + 0][lr] = wv.x; Bs[lc + 1][lr] = wv.y;
        Bs[lc + 2][lr] = wv.z; Bs[lc + 3][lr] = wv.w;
        __syncthreads();
#pragma unroll
        for (int kk = 0; kk < 16; ++kk) {
            const float4 a = *(const float4*)&As[kk][ty << 2];
            const float4 b = *(const float4*)&Bs[kk][tx << 2];
            acc[0][0] += a.x * b.x; acc[0][1] += a.x * b.y; acc[0][2] += a.x * b.z; acc[0][3] += a.x * b.w;
            acc[1][0] += a.y * b.x; acc[1][1] += a.y * b.y; acc[1][2] += a.y * b.z; acc[1][3] += a.y * b.w;
            acc[2][0] += a.z * b.x; acc[2][1] += a.z * b.y; acc[2][2] += a.z * b.z; acc[2][3] += a.z * b.w;
            acc[3][0] += a.w * b.x; acc[3][1] += a.w * b.y; acc[3][2] += a.w * b.z; acc[3][3] += a.w * b.w;
        }
    }
#pragma unroll
    for (int i = 0; i < 4; ++i) {
        float4 o;
        o.x = acc[i][0]; o.y = acc[i][1]; o.z = acc[i][2]; o.w = acc[i][3];
        *(float4*)&C[(size_t)(m0 + (ty << 2) + i) * N + n0 + (tx << 2)] = o;
    }
}

#define SW(row, seg) ((((seg) ^ (((row) + ((row) >> 4)) & 15)) << 2))

__global__ __launch_bounds__(256) void flash_f32(
    const float* __restrict__ Q, const float* __restrict__ K,
    const float* __restrict__ V, float* __restrict__ O) {
    __shared__ float Qs[64 * 64];
    __shared__ float KPs[64 * 64];
    __shared__ float Vs[64 * 64];
    const int t = threadIdx.x;
    const int tx = t & 15, ty = t >> 4;
    const int qt = blockIdx.x, h = blockIdx.y, b = blockIdx.z;
    const int q0 = qt << 6;
    const size_t hbase = (size_t)b * L_SEQ * D_MODEL + (size_t)h * D_HEAD;
#pragma unroll
    for (int i = 0; i < 4; ++i) {
        const int idx = t + (i << 8);
        const int rr = idx >> 4, seg = idx & 15;
        const float4 qv = *(const float4*)&Q[hbase + (size_t)(q0 + rr) * D_MODEL + (seg << 2)];
        *(float4*)&Qs[rr * 64 + SW(rr, seg)] = qv;
    }
    float m[4], lr_[4], oacc[4][4];
#pragma unroll
    for (int i = 0; i < 4; ++i) {
        m[i] = -INFINITY; lr_[i] = 0.f;
#pragma unroll
        for (int j = 0; j < 4; ++j) oacc[i][j] = 0.f;
    }
    const int ntile = qt + 1;
    for (int kt = 0; kt < ntile; ++kt) {
        const int kv0 = kt << 6;
        __syncthreads();
#pragma unroll
        for (int i = 0; i < 4; ++i) {
            const int idx = t + (i << 8);
            const int rr = idx >> 4, seg = idx & 15;
            const float4 kv = *(const float4*)&K[hbase + (size_t)(kv0 + rr) * D_MODEL + (seg << 2)];
            const float4 vv = *(const float4*)&V[hbase + (size_t)(kv0 + rr) * D_MODEL + (seg << 2)];
            *(float4*)&KPs[rr * 64 + SW(rr, seg)] = kv;
            *(float4*)&Vs[rr * 64 + SW(rr, seg)] = vv;
        }
        __syncthreads();
        float s[4][4];
#pragma unroll
        for (int i = 0; i < 4; ++i)
#pragma unroll
            for (int j = 0; j < 4; ++j) s[i][j] = 0.f;
#pragma unroll
        for (int seg = 0; seg < 16; ++seg) {
            float4 qv[4], kv[4];
#pragma unroll
            for (int i = 0; i < 4; ++i) {
                const int R = (ty << 2) + i;
                qv[i] = *(const float4*)&Qs[R * 64 + SW(R, seg)];
            }
#pragma unroll
            for (int j = 0; j < 4; ++j) {
                const int Cc = (tx << 2) + j;
                kv[j] = *(const float4*)&KPs[Cc * 64 + SW(Cc, seg)];
            }
#pragma unroll
            for (int i = 0; i < 4; ++i)
#pragma unroll
                for (int j = 0; j < 4; ++j)
                    s[i][j] += qv[i].x * kv[j].x + qv[i].y * kv[j].y +
                               qv[i].z * kv[j].z + qv[i].w * kv[j].w;
        }
        const bool diag = (kt == qt);
        float tm[4];
#pragma unroll
        for (int i = 0; i < 4; ++i) {
            tm[i] = -INFINITY;
#pragma unroll
            for (int j = 0; j < 4; ++j) {
                float sval = s[i][j] * 0.125f;
                if (diag) {
                    const int Cg = kv0 + (tx << 2) + j;
                    const int Rg = q0 + (ty << 2) + i;
                    if (Cg > Rg) sval = -INFINITY;
                }
                s[i][j] = sval;
                tm[i] = fmaxf(tm[i], sval);
            }
            tm[i] = fmaxf(tm[i], __shfl_xor(tm[i], 1));
            tm[i] = fmaxf(tm[i], __shfl_xor(tm[i], 2));
            tm[i] = fmaxf(tm[i], __shfl_xor(tm[i], 4));
            tm[i] = fmaxf(tm[i], __shfl_xor(tm[i], 8));
        }
        float p[4][4];
#pragma unroll
        for (int i = 0; i < 4; ++i) {
            const float mn = fmaxf(m[i], tm[i]);
            const float alpha = __expf(m[i] - mn);
            m[i] = mn;
            float psum = 0.f;
#pragma unroll
            for (int j = 0; j < 4; ++j) {
                p[i][j] = __expf(s[i][j] - mn);
                psum += p[i][j];
            }
            psum += __shfl_xor(psum, 1);
            psum += __shfl_xor(psum, 2);
            psum += __shfl_xor(psum, 4);
            psum += __shfl_xor(psum, 8);
            lr_[i] = lr_[i] * alpha + psum;
#pragma unroll
            for (int j = 0; j < 4; ++j) oacc[i][j] *= alpha;
        }
        __syncthreads();
#pragma unroll
        for (int i = 0; i < 4; ++i) {
            const int R = (ty << 2) + i;
            float4 pv;
            pv.x = p[i][0]; pv.y = p[i][1]; pv.z = p[i][2]; pv.w = p[i][3];
            *(float4*)&KPs[R * 64 + SW(R, tx)] = pv;
        }
        __syncthreads();
#pragma unroll
        for (int cs = 0; cs < 16; ++cs) {
            float pc[4][4];
            float4 vr[4];
#pragma unroll
            for (int i = 0; i < 4; ++i) {
                const int R = (ty << 2) + i;
                const float4 pr = *(const float4*)&KPs[R * 64 + SW(R, cs)];
                pc[i][0] = pr.x; pc[i][1] = pr.y; pc[i][2] = pr.z; pc[i][3] = pr.w;
            }
#pragma unroll
            for (int cc = 0; cc < 4; ++cc) {
                const int Cr = (cs << 2) + cc;
                vr[cc] = *(const float4*)&Vs[Cr * 64 + SW(Cr, tx)];
            }
#pragma unroll
            for (int i = 0; i < 4; ++i)
#pragma unroll
                for (int cc = 0; cc < 4; ++cc) {
                    oacc[i][0] += pc[i][cc] * vr[cc].x;
                    oacc[i][1] += pc[i][cc] * vr[cc].y;
                    oacc[i][2] += pc[i][cc] * vr[cc].z;
                    oacc[i][3] += pc[i][cc] * vr[cc].w;
                }
        }
    }
#pragma unroll
    for (int i = 0; i < 4; ++i) {
        const int R = (ty << 2) + i;
        const float invl = 1.0f / lr_[i];
        float4 o;
        o.x = oacc[i][0] * invl; o.y = oacc[i][1] * invl;
        o.z = oacc[i][2] * invl; o.w = oacc[i][3] * invl;
        *(float4*)&O[hbase + (size_t)(q0 + R) * D_MODEL + (tx << 2)] = o;
    }
}

// ---------------------------------------------------------------------------
extern "C" void kernel_launch(void* const* d_in, const int* in_sizes, int n_in,
                              void* d_out, int out_size, void* d_ws, size_t ws_size,
                              hipStream_t stream) {
    const float* x  = (const float*)d_in[0];
    const float* Wq = (const float*)d_in[2];
    const float* Wk = (const float*)d_in[3];
    const float* Wv = (const float*)d_in[4];
    const float* Wo = (const float*)d_in[5];
    float* out = (float*)d_out;

    if (ws_size >= 83886080ull) {
        char* ws = (char*)d_ws;
        u16* x2  = (u16*)(ws);                // 16 MB, reused as A2 after QKV
        u16* Wq2 = (u16*)(ws + 16777216);     // Wq2/Wk2/Wv2/Wo2 contiguous 4MB each
        u16* Wo2 = (u16*)(ws + 29360128);
        u16* Qh  = (u16*)(ws + 33554432);
        u16* Ql  = (u16*)(ws + 41943040);
        u16* Kh  = (u16*)(ws + 50331648);
        u16* Kl  = (u16*)(ws + 58720256);
        u16* Vth = (u16*)(ws + 67108864);
        u16* Vh  = (u16*)d_out;               // scratch, rewritten by final GEMM

        hipFuncSetAttribute((const void*)flash_mfma,
                            hipFuncAttributeMaxDynamicSharedMemorySize, 81920);
        hipFuncSetAttribute((const void*)gemm256_qkv,
                            hipFuncAttributeMaxDynamicSharedMemorySize, 114688);

        split_all<<<8192, 256, 0, stream>>>(x, Wq, Wk, Wv, Wo, x2, Wq2);
        gemm256_qkv<<<256, 512, 114688, stream>>>(x2, Wq2, Qh, Ql, Kh, Kl, Vh);
        vtrans<<<dim3(16, 16, 2), 128, 0, stream>>>(Vh, Vth);
        flash_mfma<<<256, 512, 81920, stream>>>(Qh, Ql, Kh, Kl, Vth, x2);
        gemm_wo<<<512, 256, 0, stream>>>(x2, Wo2, out);
    } else {
        const int M = B_SIZE * L_SEQ, N = D_MODEL, Kd = D_MODEL;
        float* Qw = (float*)d_ws;
        float* Kw = Qw + (size_t)M * D_MODEL;
        float* Vw = Kw + (size_t)M * D_MODEL;
        float* Aw = Vw + (size_t)M * D_MODEL;
        dim3 gg(N / 64, M / 64);
        gemm_bt_f32<<<gg, 256, 0, stream>>>(x, Wq, Qw, M, N, Kd);
        gemm_bt_f32<<<gg, 256, 0, stream>>>(x, Wk, Kw, M, N, Kd);
        gemm_bt_f32<<<gg, 256, 0, stream>>>(x, Wv, Vw, M, N, Kd);
        flash_f32<<<dim3(L_SEQ / 64, N_HEAD, B_SIZE), 256, 0, stream>>>(Qw, Kw, Vw, Aw);
        gemm_bt_f32<<<gg, 256, 0, stream>>>(Aw, Wo, out, M, N, Kd);
    }
}

// Round 11
// 222.403 us; speedup vs baseline: 1.1278x; 1.0422x over previous
//
#include <hip/hip_runtime.h>
#include <math.h>

#define L_SEQ  2048
#define D_MODEL 1024
#define N_HEAD 16
#define D_HEAD 64
#define B_SIZE 2

typedef __attribute__((ext_vector_type(8))) short bf16x8;
typedef __attribute__((ext_vector_type(4))) float f32x4;
typedef unsigned short u16;
typedef unsigned int u32;

__device__ __forceinline__ f32x4 mfma16(bf16x8 a, bf16x8 b, f32x4 c) {
    return __builtin_amdgcn_mfma_f32_16x16x32_bf16(a, b, c, 0, 0, 0);
}

__device__ __forceinline__ u16 f2bf(float x) {
    u32 u = __builtin_bit_cast(u32, x);
    u32 r = (u + 0x7FFFu + ((u >> 16) & 1u)) >> 16;
    return (u16)r;
}
__device__ __forceinline__ u16 f2bf_t(float x) {  // truncate (P only)
    return (u16)(__builtin_bit_cast(u32, x) >> 16);
}
__device__ __forceinline__ float bf2f(u16 h) {
    u32 u = ((u32)h) << 16;
    return __builtin_bit_cast(float, u);
}
__device__ __forceinline__ float fexp2(float x) {  // 2^x via v_exp_f32
    float r;
    asm("v_exp_f32 %0, %1" : "=v"(r) : "v"(x));
    return r;
}

__device__ __forceinline__ void gl2lds16(const void* g, void* l) {
    __builtin_amdgcn_global_load_lds(
        (__attribute__((address_space(1))) void*)(g),
        (__attribute__((address_space(3))) void*)(l), 16, 0, 0);
}

// ---------------------------------------------------------------------------
// fused split: x (4096 blocks) + 4 weights (4096 blocks) -> [hi|lo] bf16 rows
// ---------------------------------------------------------------------------
__global__ __launch_bounds__(256) void split_all(
    const float* __restrict__ x,
    const float* __restrict__ w0, const float* __restrict__ w1,
    const float* __restrict__ w2, const float* __restrict__ w3,
    u16* __restrict__ x2, u16* __restrict__ wout) {
    const int id = blockIdx.x;
    const float* in;
    u16* out;
    int idx;
    if (id < 4096) {
        in = x; out = x2; idx = id * 256 + threadIdx.x;
    } else {
        const int wi = (id - 4096) >> 10;
        const int blk = (id - 4096) & 1023;
        in = (wi == 0) ? w0 : (wi == 1) ? w1 : (wi == 2) ? w2 : w3;
        out = wout + (size_t)wi * 2097152;
        idx = blk * 256 + threadIdx.x;
    }
    const int c4 = idx << 2;
    const int r = c4 >> 10, c = c4 & 1023;
    float4 v = *(const float4*)(in + c4);
    u16 h0 = f2bf(v.x), h1 = f2bf(v.y), h2 = f2bf(v.z), h3 = f2bf(v.w);
    ushort4 hi = make_ushort4(h0, h1, h2, h3);
    ushort4 lo = make_ushort4(f2bf(v.x - bf2f(h0)), f2bf(v.y - bf2f(h1)),
                              f2bf(v.z - bf2f(h2)), f2bf(v.w - bf2f(h3)));
    *(ushort4*)(out + (size_t)r * 2048 + c) = hi;
    *(ushort4*)(out + (size_t)r * 2048 + 1024 + c) = lo;
}

// ---------------------------------------------------------------------------
// 8-phase 256x192 QKV GEMM — 256 blocks, counted vmcnt(3). (R10, unchanged
// except Q scale now folds 1/ln2 for the exp2-domain flash softmax.)
// ---------------------------------------------------------------------------
__device__ __forceinline__ int kaOf(int x) {
    return (((x >> 4) == 1) ? 1024 : 0) + ((x << 6) & 1023);
}
__device__ __forceinline__ int kwOf(int x) {
    return (((x >> 4) == 0) ? 1024 : 0) + ((x << 6) & 1023);
}

#define SBAR()  do { __builtin_amdgcn_sched_barrier(0); \
                     __builtin_amdgcn_s_barrier(); \
                     __builtin_amdgcn_sched_barrier(0); } while (0)

__global__ __launch_bounds__(512) void gemm256_qkv(
    const u16* __restrict__ A2, const u16* __restrict__ Wall,
    u16* __restrict__ Qh, u16* __restrict__ Ql,
    u16* __restrict__ Kh, u16* __restrict__ Kl,
    u16* __restrict__ Vh) {
    extern __shared__ __align__(16) u16 smem[];

    const int t = threadIdx.x, l = t & 63, wid = t >> 6;
    const int id = blockIdx.x;
    const int wg = (id & 7) * 32 + (id >> 3);
    const int mt = wg >> 4, ntile = wg & 15;
    const int m0 = mt << 8, n0 = ntile * 192;

    const int wrH = wid >> 2;
    const int wcN = (wid & 3) * 48;

    f32x4 acc[8][3];
#pragma unroll
    for (int i = 0; i < 8; ++i)
#pragma unroll
        for (int j = 0; j < 3; ++j) acc[i][j] = (f32x4){0.f, 0.f, 0.f, 0.f};

    const int sr = t >> 3, sc = t & 7;

    auto stageA = [&](int x, int half) {
        const int koff = kaOf(x);
        u16* dst = smem + (x & 1) * 16384 + half * 8192;
        const u16* srcb = A2 + (size_t)(m0 + half * 128) * 2048 + koff;
#pragma unroll
        for (int p = 0; p < 2; ++p) {
            const int r = sr + p * 64;
            const int ck = sc ^ (r & 7);
            gl2lds16(srcb + (size_t)r * 2048 + ck * 8, dst + t * 8 + p * 4096);
        }
    };
    auto stageB = [&](int x, int third) {
        const int koff = kwOf(x);
        u16* dst = smem + 32768 + (x & 1) * 12288 + third * 4096;
        const int r = sr;
        const int ck = sc ^ (r & 7);
        const u16* src = Wall + (size_t)(n0 + third * 64 + r) * 2048 + koff + ck * 8;
        gl2lds16(src, dst + t * 8);
    };
    auto dsA = [&](int s, int mh, int kc, bf16x8 af[4]) {
        const u16* Ab = smem + s * 16384 + wrH * 8192;
#pragma unroll
        for (int f = 0; f < 4; ++f) {
            const int r = mh * 64 + f * 16 + (l & 15);
            const int c8 = kc * 4 + (l >> 4);
            af[f] = *(const bf16x8*)&Ab[r * 64 + ((c8 ^ (r & 7)) << 3)];
        }
    };
    auto dsB = [&](int s, int kc, bf16x8 bfr[3]) {
        const u16* Bb = smem + 32768 + s * 12288;
#pragma unroll
        for (int f = 0; f < 3; ++f) {
            const int row = wcN + f * 16 + (l & 15);
            const int third = row >> 6, lr = row & 63;
            const int c8 = kc * 4 + (l >> 4);
            bfr[f] = *(const bf16x8*)&Bb[third * 4096 + lr * 64 + ((c8 ^ (lr & 7)) << 3)];
        }
    };

    stageB(0, 0); stageB(0, 1); stageB(0, 2);
    stageA(0, 0); stageA(0, 1);
    stageB(1, 0); stageB(1, 1); stageB(1, 2);
    __builtin_amdgcn_sched_barrier(0);
    asm volatile("s_waitcnt vmcnt(3)" ::: "memory");
    __builtin_amdgcn_s_barrier();
    __builtin_amdgcn_sched_barrier(0);

    const int NT = 48;
    bf16x8 breg0[3], breg1[3], af[4];
    for (int tt = 0; tt < NT; ++tt) {
        const int s = tt & 1;
        dsA(s, 0, 0, af); dsB(s, 0, breg0);
        if (tt + 1 < NT) stageA(tt + 1, 0);
        SBAR();
        __builtin_amdgcn_s_setprio(1);
#pragma unroll
        for (int f = 0; f < 4; ++f)
#pragma unroll
            for (int fn = 0; fn < 3; ++fn)
                acc[f][fn] = mfma16(af[f], breg0[fn], acc[f][fn]);
        __builtin_amdgcn_s_setprio(0);
        SBAR();
        dsA(s, 0, 1, af); dsB(s, 1, breg1);
        if (tt + 1 < NT) stageA(tt + 1, 1);
        SBAR();
        __builtin_amdgcn_s_setprio(1);
#pragma unroll
        for (int f = 0; f < 4; ++f)
#pragma unroll
            for (int fn = 0; fn < 3; ++fn)
                acc[f][fn] = mfma16(af[f], breg1[fn], acc[f][fn]);
        __builtin_amdgcn_s_setprio(0);
        SBAR();
        dsA(s, 1, 0, af);
        if (tt + 2 < NT) { stageB(tt + 2, 0); stageB(tt + 2, 1); }
        SBAR();
        __builtin_amdgcn_s_setprio(1);
#pragma unroll
        for (int f = 0; f < 4; ++f)
#pragma unroll
            for (int fn = 0; fn < 3; ++fn)
                acc[4 + f][fn] = mfma16(af[f], breg0[fn], acc[4 + f][fn]);
        __builtin_amdgcn_s_setprio(0);
        SBAR();
        dsA(s, 1, 1, af);
        if (tt + 2 < NT) stageB(tt + 2, 2);
        SBAR();
        __builtin_amdgcn_s_setprio(1);
#pragma unroll
        for (int f = 0; f < 4; ++f)
#pragma unroll
            for (int fn = 0; fn < 3; ++fn)
                acc[4 + f][fn] = mfma16(af[f], breg1[fn], acc[4 + f][fn]);
        __builtin_amdgcn_s_setprio(0);
        __builtin_amdgcn_sched_barrier(0);
        if (tt + 2 < NT) {
            asm volatile("s_waitcnt vmcnt(3)" ::: "memory");
        } else if (tt + 1 < NT) {
            asm volatile("s_waitcnt vmcnt(0)" ::: "memory");
        }
        __builtin_amdgcn_s_barrier();
        __builtin_amdgcn_sched_barrier(0);
    }

    // epilogue: Q scaled by 0.125/ln2 (exp2-domain softmax); V hi-only
#pragma unroll
    for (int fm = 0; fm < 8; ++fm)
#pragma unroll
        for (int fn = 0; fn < 3; ++fn)
#pragma unroll
            for (int rg = 0; rg < 4; ++rg) {
                const int gm = m0 + wrH * 128 + fm * 16 + ((l >> 4) << 2) + rg;
                const int gn = n0 + wcN + fn * 16 + (l & 15);
                const int z = gn >> 10, col = gn & 1023;
                float v = acc[fm][fn][rg];
                if (z == 0) v *= 0.18033688f;  // 0.125 * (1/ln2)
                const int b = gm >> 11, lq = gm & 2047;
                const int h = col >> 6, d = col & 63;
                const size_t oi = (((size_t)(b * 16 + h)) * 2048 + lq) * 64 + d;
                const u16 hi = f2bf(v);
                if (z == 0) { Qh[oi] = hi; Ql[oi] = f2bf(v - bf2f(hi)); }
                else if (z == 1) { Kh[oi] = hi; Kl[oi] = f2bf(v - bf2f(hi)); }
                else { Vh[oi] = hi; }
            }
}

// ---------------------------------------------------------------------------
// Wo GEMM: 128x64 tiles, 512 blocks (2/CU), XCD-chunked. BK=32, bf16x3.
// ---------------------------------------------------------------------------
__global__ __launch_bounds__(256) void gemm_wo(
    const u16* __restrict__ A2, const u16* __restrict__ W2,
    float* __restrict__ Cout) {
    __shared__ __align__(16) u16 As[128 * 32];
    __shared__ __align__(16) u16 Ws2[64 * 32];
    const int t = threadIdx.x, l = t & 63, wid = t >> 6;
    const int id = blockIdx.x;
    const int nid = ((id & 7) << 6) + (id >> 3);
    const int m0 = (nid >> 4) << 7;
    const int n0 = (nid & 15) << 6;
    const int wm = wid >> 1, wn = wid & 1;

    f32x4 acc[4][2];
#pragma unroll
    for (int i = 0; i < 4; ++i)
#pragma unroll
        for (int j = 0; j < 2; ++j) acc[i][j] = (f32x4){0.f, 0.f, 0.f, 0.f};

    const int arow0 = t >> 2, ach0 = (t & 3) ^ (arow0 & 3);
    const int arow1 = (t + 256) >> 2, ach1 = (t & 3) ^ (arow1 & 3);
    const int brow = t >> 2, bch = (t & 3) ^ (brow & 3);

    for (int k0 = 0; k0 < 3072; k0 += 32) {
        const int rg3 = k0 >> 10, kb = k0 & 1023;
        const int ka = (rg3 == 1 ? 1024 : 0) + kb;
        const int kw = (rg3 == 0 ? 1024 : 0) + kb;
        __syncthreads();
        gl2lds16(A2 + (size_t)(m0 + arow0) * 2048 + ka + ach0 * 8,
                 (u16*)As + t * 8);
        gl2lds16(A2 + (size_t)(m0 + arow1) * 2048 + ka + ach1 * 8,
                 (u16*)As + (t + 256) * 8);
        if (t < 256)
            gl2lds16(W2 + (size_t)(n0 + brow) * 2048 + kw + bch * 8,
                     (u16*)Ws2 + t * 8);
        __syncthreads();
        bf16x8 af[4], bfr[2];
#pragma unroll
        for (int f = 0; f < 4; ++f) {
            const int row = wm * 64 + f * 16 + (l & 15);
            const int ch = (l >> 4) ^ (row & 3);
            af[f] = *(const bf16x8*)&As[(row << 5) + (ch << 3)];
        }
#pragma unroll
        for (int f = 0; f < 2; ++f) {
            const int rown = wn * 32 + f * 16 + (l & 15);
            const int chn = (l >> 4) ^ (rown & 3);
            bfr[f] = *(const bf16x8*)&Ws2[(rown << 5) + (chn << 3)];
        }
        __builtin_amdgcn_s_setprio(1);
#pragma unroll
        for (int fm = 0; fm < 4; ++fm)
#pragma unroll
            for (int fn = 0; fn < 2; ++fn)
                acc[fm][fn] = mfma16(af[fm], bfr[fn], acc[fm][fn]);
        __builtin_amdgcn_s_setprio(0);
    }

#pragma unroll
    for (int fm = 0; fm < 4; ++fm)
#pragma unroll
        for (int fn = 0; fn < 2; ++fn)
#pragma unroll
            for (int rg = 0; rg < 4; ++rg) {
                const int gm = m0 + wm * 64 + fm * 16 + ((l >> 4) << 2) + rg;
                const int gn = n0 + wn * 32 + fn * 16 + (l & 15);
                Cout[(size_t)gm * 1024 + gn] = acc[fm][fn][rg];
            }
}

// ---------------------------------------------------------------------------
// V transpose (hi only): [B][H][L][64] -> [B][H][64][L].
// ---------------------------------------------------------------------------
__global__ __launch_bounds__(128) void vtrans(const u16* __restrict__ Vh,
                                              u16* __restrict__ Vth) {
    const int t = threadIdx.x;
    const int kt = (blockIdx.x << 1) + (t >> 6);
    const int h = blockIdx.y, b = blockIdx.z;
    const size_t base = ((size_t)(b * 16 + h)) * 131072;
    const int kv0 = kt << 6;
    const int st = t & 63;
    const int r0 = (st >> 3) << 3;
    const int c0 = (st & 7) << 3;
    ushort4 inv[8][2];
#pragma unroll
    for (int j = 0; j < 8; ++j) {
        const u16* p = Vh + base + (size_t)(kv0 + r0 + j) * 64 + c0;
        inv[j][0] = *(const ushort4*)p;
        inv[j][1] = *(const ushort4*)(p + 4);
    }
#pragma unroll
    for (int i = 0; i < 8; ++i) {
        u16 o[8];
#pragma unroll
        for (int j = 0; j < 8; ++j) {
            ushort4 vv = inv[j][i >> 2];
            const int ii = i & 3;
            o[j] = (ii == 0) ? vv.x : (ii == 1) ? vv.y : (ii == 2) ? vv.z : vv.w;
        }
        u16* q = Vth + base + (size_t)(c0 + i) * 2048 + kv0 + r0;
        *(ushort4*)q = make_ushort4(o[0], o[1], o[2], o[3]);
        *(ushort4*)(q + 4) = make_ushort4(o[4], o[5], o[6], o[7]);
    }
}

// ---------------------------------------------------------------------------
// MFMA flash attention. R11: KVBLK=128 per sync (2x 64-col sub-units, halved
// barriers), exp2-domain softmax (Q pre-scaled by 1/ln2), row-sum via
// ones-MFMA (drops sum shuffles). Paired causal tiles, fused PV, V hi-only,
// defer-max (thr 11.5 in log2), trunc-P, setprio. 512 thr; 256 blocks; 128KB.
// ---------------------------------------------------------------------------
struct QTileState {
    bf16x8 qhf[2], qlf[2];
    f32x4 oacc[4];
    float mrow[4], lrow[4];
};

__device__ __forceinline__ void qstate_init(
    QTileState& st, const u16* Qh, const u16* Ql, size_t hb, int q0, int w, int l) {
    const int rowq = q0 + (w << 4) + (l & 15);
#pragma unroll
    for (int kc = 0; kc < 2; ++kc) {
        const size_t off = hb + (size_t)rowq * 64 + (((kc << 2) + (l >> 4)) << 3);
        st.qhf[kc] = *(const bf16x8*)(Qh + off);
        st.qlf[kc] = *(const bf16x8*)(Ql + off);
    }
#pragma unroll
    for (int i = 0; i < 4; ++i) {
        st.oacc[i] = (f32x4){0.f, 0.f, 0.f, 0.f};
        st.mrow[i] = -INFINITY;
        st.lrow[i] = 0.f;
    }
}

// QK^T (3-product, log2 domain) + online softmax max/rescale; fills pb.
__device__ __forceinline__ void fa_qk_softmax(
    QTileState& st, const u16* bKh, const u16* bKl,
    int kv0, int q0, int w, int l, u16 pb[4][4]) {
    f32x4 sacc[4];
#pragma unroll
    for (int nf = 0; nf < 4; ++nf) sacc[nf] = (f32x4){0.f, 0.f, 0.f, 0.f};
#pragma unroll
    for (int kc = 0; kc < 2; ++kc) {
        bf16x8 kh_[4], kl_[4];
#pragma unroll
        for (int nf = 0; nf < 4; ++nf) {
            const int row = (nf << 4) + (l & 15);
            const int ch = ((kc << 2) + (l >> 4)) ^ (row & 7);
            kh_[nf] = *(const bf16x8*)&bKh[(row << 6) + (ch << 3)];
            kl_[nf] = *(const bf16x8*)&bKl[(row << 6) + (ch << 3)];
        }
        __builtin_amdgcn_s_setprio(1);
#pragma unroll
        for (int nf = 0; nf < 4; ++nf) {
            sacc[nf] = mfma16(st.qhf[kc], kl_[nf], sacc[nf]);
            sacc[nf] = mfma16(st.qlf[kc], kh_[nf], sacc[nf]);
            sacc[nf] = mfma16(st.qhf[kc], kh_[nf], sacc[nf]);
        }
        __builtin_amdgcn_s_setprio(0);
    }

    const bool domask = (kv0 + 63) > (q0 + (w << 4));
    float pm[4] = {-INFINITY, -INFINITY, -INFINITY, -INFINITY};
    float sv[4][4];
#pragma unroll
    for (int nf = 0; nf < 4; ++nf)
#pragma unroll
        for (int rg = 0; rg < 4; ++rg) {
            float x = sacc[nf][rg];
            if (domask) {
                const int colg = kv0 + (nf << 4) + (l & 15);
                const int rowg = q0 + (w << 4) + ((l >> 4) << 2) + rg;
                if (colg > rowg) x = -INFINITY;
            }
            sv[nf][rg] = x;
            pm[rg] = fmaxf(pm[rg], x);
        }
#pragma unroll
    for (int rg = 0; rg < 4; ++rg) {
        float v = pm[rg];
        v = fmaxf(v, __shfl_xor(v, 1));
        v = fmaxf(v, __shfl_xor(v, 2));
        v = fmaxf(v, __shfl_xor(v, 4));
        v = fmaxf(v, __shfl_xor(v, 8));
        pm[rg] = v;
    }
    // defer-max (log2 units): rescale only when max grew by > 11.5
    const float need = fmaxf(fmaxf(pm[0] - st.mrow[0], pm[1] - st.mrow[1]),
                             fmaxf(pm[2] - st.mrow[2], pm[3] - st.mrow[3]));
    if (__any(need > 11.5f)) {
#pragma unroll
        for (int rg = 0; rg < 4; ++rg) {
            const float mn = fmaxf(st.mrow[rg], pm[rg]);
            const float al = fexp2(st.mrow[rg] - mn);
            st.mrow[rg] = mn;
            st.lrow[rg] *= al;
#pragma unroll
            for (int nf = 0; nf < 4; ++nf) st.oacc[nf][rg] *= al;
        }
    }
#pragma unroll
    for (int nf = 0; nf < 4; ++nf)
#pragma unroll
        for (int rg = 0; rg < 4; ++rg)
            pb[nf][rg] = f2bf_t(fexp2(sv[nf][rg] - st.mrow[rg]));
}

__device__ __forceinline__ void fa_writeP(const u16 pb[4][4], int l, u16* Pw) {
#pragma unroll
    for (int nf = 0; nf < 4; ++nf)
#pragma unroll
        for (int rg = 0; rg < 4; ++rg) {
            const int r = ((l >> 4) << 2) + rg;
            const int c = (nf << 4) + (l & 15);
            const int ch = (c >> 3) ^ (r & 7);
            Pw[(r << 6) + (ch << 3) + (c & 7)] = pb[nf][rg];
        }
}

__device__ __forceinline__ void fa_epilogue(
    QTileState& st, u16* A2, int g, int q0, int w, int l) {
    const int b = g >> 4, h = g & 15;
    float inv[4];
#pragma unroll
    for (int rg = 0; rg < 4; ++rg) inv[rg] = 1.0f / st.lrow[rg];
#pragma unroll
    for (int nf = 0; nf < 4; ++nf)
#pragma unroll
        for (int rg = 0; rg < 4; ++rg) {
            const int rowq = q0 + (w << 4) + ((l >> 4) << 2) + rg;
            const int m = (b << 11) + rowq;
            const int d = (nf << 4) + (l & 15);
            const float v = st.oacc[nf][rg] * inv[rg];
            const u16 hi = f2bf(v);
            const u16 lo = f2bf(v - bf2f(hi));
            const size_t rb = (size_t)m * 2048;
            A2[rb + h * 64 + d] = hi;
            A2[rb + 1024 + h * 64 + d] = lo;
        }
}

__global__ __launch_bounds__(512) void flash_mfma(
    const u16* __restrict__ Qh, const u16* __restrict__ Ql,
    const u16* __restrict__ Kh, const u16* __restrict__ Kl,
    const u16* __restrict__ Vth,
    u16* __restrict__ A2) {
    extern __shared__ __align__(16) u16 smem[];
    // pair-buffer s at s*24576: slot(0/1)*12288 -> {Kh, Kl(+4096), Vh(+8192)}
    u16* const PsB = smem + 49152;   // 8 waves x 1024
    u16* const PsA = smem + 57344;   // 8 waves x 1024

    const int t = threadIdx.x, l = t & 63, w = t >> 6;
    const int id = blockIdx.x;
    const int nid = ((id & 7) << 5) + (id >> 3);
    const int g = nid >> 3;
    const int p = nid & 7;
    const int q0A = p << 7;
    const int q0B = (15 - p) << 7;
    const size_t hb = (size_t)g * 131072;

    QTileState stA, stB;
    qstate_init(stA, Qh, Ql, hb, q0A, w, l);
    qstate_init(stB, Qh, Ql, hb, q0B, w, l);

    const int row_s = t >> 3;
    const int cs_s = (t & 7) ^ (row_s & 7);

    auto stage1 = [&](int s, int slot, int kt_) {
        u16* base = smem + s * 24576 + slot * 12288;
        const int kv0s = kt_ << 6;
        const size_t koff = hb + (size_t)(kv0s + row_s) * 64 + cs_s * 8;
        gl2lds16(Kh + koff, base + t * 8);
        gl2lds16(Kl + koff, base + 4096 + t * 8);
        const size_t voff = hb + (size_t)row_s * 2048 + kv0s + cs_s * 8;
        gl2lds16(Vth + voff, base + 8192 + t * 8);
    };

    u16* const PwB = PsB + (w << 10);
    u16* const PwA = PsA + (w << 10);
    const int ntA = (p << 1) + 2;     // even, 2..16
    const int ntB = 32 - (p << 1);    // even, 18..32
    const int NB = ntB >> 1;

    const short ob = (short)0x3F80;   // bf16 1.0
    const bf16x8 ones = {ob, ob, ob, ob, ob, ob, ob, ob};

    auto unit = [&](int s, int slot, int kt_) {
        const u16* bKh = smem + s * 24576 + slot * 12288;
        const u16* bKl = bKh + 4096;
        const u16* bVh = bKh + 8192;
        const int kv0 = kt_ << 6;
        const bool aB = kv0 <= q0B + (w << 4) + 15;
        const bool aA = (kt_ < ntA) && (kv0 <= q0A + (w << 4) + 15);
        if (!aB && !aA) return;
        u16 pbB[4][4], pbA[4][4];
        if (aB) fa_qk_softmax(stB, bKh, bKl, kv0, q0B, w, l, pbB);
        if (aA) fa_qk_softmax(stA, bKh, bKl, kv0, q0A, w, l, pbA);
        if (aB) fa_writeP(pbB, l, PwB);
        if (aA) fa_writeP(pbA, l, PwA);
        f32x4 lsB = {0.f, 0.f, 0.f, 0.f}, lsA = {0.f, 0.f, 0.f, 0.f};
#pragma unroll
        for (int kc = 0; kc < 2; ++kc) {
            bf16x8 vh_[4];
#pragma unroll
            for (int nf = 0; nf < 4; ++nf) {
                const int row = (nf << 4) + (l & 15);
                const int cv = ((kc << 2) + (l >> 4)) ^ (row & 7);
                vh_[nf] = *(const bf16x8*)&bVh[(row << 6) + (cv << 3)];
            }
            const int r = l & 15;
            const int chp = ((kc << 2) + (l >> 4)) ^ (r & 7);
            __builtin_amdgcn_s_setprio(1);
            if (aB) {
                const bf16x8 pa = *(const bf16x8*)&PwB[(r << 6) + (chp << 3)];
#pragma unroll
                for (int nf = 0; nf < 4; ++nf)
                    stB.oacc[nf] = mfma16(pa, vh_[nf], stB.oacc[nf]);
                lsB = mfma16(pa, ones, lsB);   // row-sum of truncated P
            }
            if (aA) {
                const bf16x8 pa = *(const bf16x8*)&PwA[(r << 6) + (chp << 3)];
#pragma unroll
                for (int nf = 0; nf < 4; ++nf)
                    stA.oacc[nf] = mfma16(pa, vh_[nf], stA.oacc[nf]);
                lsA = mfma16(pa, ones, lsA);
            }
            __builtin_amdgcn_s_setprio(0);
        }
        if (aB) {
#pragma unroll
            for (int rg = 0; rg < 4; ++rg) stB.lrow[rg] += lsB[rg];
        }
        if (aA) {
#pragma unroll
            for (int rg = 0; rg < 4; ++rg) stA.lrow[rg] += lsA[rg];
        }
    };

    stage1(0, 0, 0); stage1(0, 1, 1);
    __syncthreads();
    for (int j = 0; j < NB; ++j) {
        const int s = j & 1;
        if (j + 1 < NB) { stage1(s ^ 1, 0, 2 * j + 2); stage1(s ^ 1, 1, 2 * j + 3); }
        unit(s, 0, 2 * j);
        unit(s, 1, 2 * j + 1);
        __syncthreads();
    }

    fa_epilogue(stA, A2, g, q0A, w, l);
    fa_epilogue(stB, A2, g, q0B, w, l);
}

// ===========================================================================
// Fallback fp32 path
// ===========================================================================
__global__ __launch_bounds__(256) void gemm_bt_f32(
    const float* __restrict__ A, const float* __restrict__ W,
    float* __restrict__ C, int M, int N, int K) {
    __shared__ float As[16][68];
    __shared__ float Bs[16][68];
    const int t = threadIdx.x;
    const int tx = t & 15, ty = t >> 4;
    const int m0 = blockIdx.y << 6, n0 = blockIdx.x << 6;
    const int lr = t >> 2, lc = (t & 3) << 2;
    const float* Ag = A + (size_t)(m0 + lr) * K + lc;
    const float* Wg = W + (size_t)(n0 + lr) * K + lc;
    float acc[4][4];
#pragma unroll
    for (int i = 0; i < 4; ++i)
#pragma unroll
        for (int j = 0; j < 4; ++j) acc[i][j] = 0.f;
    for (int k0 = 0; k0 < K; k0 += 16) {
        const float4 av = *(const float4*)(Ag + k0);
        const float4 wv = *(const float4*)(Wg + k0);
        __syncthreads();
        As[lc + 0][lr] = av.x; As[lc + 1][lr] = av.y;
        As[lc + 2][lr] = av.z; As[lc + 3][lr] = av.w;
        Bs[lc + 0][lr] = wv.x; Bs[lc + 1][lr] = wv.y;
        Bs[lc + 2][lr] = wv.z; Bs[lc + 3][lr] = wv.w;
        __syncthreads();
#pragma unroll
        for (int kk = 0; kk < 16; ++kk) {
            const float4 a = *(const float4*)&As[kk][ty << 2];
            const float4 b = *(const float4*)&Bs[kk][tx << 2];
            acc[0][0] += a.x * b.x; acc[0][1] += a.x * b.y; acc[0][2] += a.x * b.z; acc[0][3] += a.x * b.w;
            acc[1][0] += a.y * b.x; acc[1][1] += a.y * b.y; acc[1][2] += a.y * b.z; acc[1][3] += a.y * b.w;
            acc[2][0] += a.z * b.x; acc[2][1] += a.z * b.y; acc[2][2] += a.z * b.z; acc[2][3] += a.z * b.w;
            acc[3][0] += a.w * b.x; acc[3][1] += a.w * b.y; acc[3][2] += a.w * b.z; acc[3][3] += a.w * b.w;
        }
    }
#pragma unroll
    for (int i = 0; i < 4; ++i) {
        float4 o;
        o.x = acc[i][0]; o.y = acc[i][1]; o.z = acc[i][2]; o.w = acc[i][3];
        *(float4*)&C[(size_t)(m0 + (ty << 2) + i) * N + n0 + (tx << 2)] = o;
    }
}

#define SW(row, seg) ((((seg) ^ (((row) + ((row) >> 4)) & 15)) << 2))

__global__ __launch_bounds__(256) void flash_f32(
    const float* __restrict__ Q, const float* __restrict__ K,
    const float* __restrict__ V, float* __restrict__ O) {
    __shared__ float Qs[64 * 64];
    __shared__ float KPs[64 * 64];
    __shared__ float Vs[64 * 64];
    const int t = threadIdx.x;
    const int tx = t & 15, ty = t >> 4;
    const int qt = blockIdx.x, h = blockIdx.y, b = blockIdx.z;
    const int q0 = qt << 6;
    const size_t hbase = (size_t)b * L_SEQ * D_MODEL + (size_t)h * D_HEAD;
#pragma unroll
    for (int i = 0; i < 4; ++i) {
        const int idx = t + (i << 8);
        const int rr = idx >> 4, seg = idx & 15;
        const float4 qv = *(const float4*)&Q[hbase + (size_t)(q0 + rr) * D_MODEL + (seg << 2)];
        *(float4*)&Qs[rr * 64 + SW(rr, seg)] = qv;
    }
    float m[4], lr_[4], oacc[4][4];
#pragma unroll
    for (int i = 0; i < 4; ++i) {
        m[i] = -INFINITY; lr_[i] = 0.f;
#pragma unroll
        for (int j = 0; j < 4; ++j) oacc[i][j] = 0.f;
    }
    const int ntile = qt + 1;
    for (int kt = 0; kt < ntile; ++kt) {
        const int kv0 = kt << 6;
        __syncthreads();
#pragma unroll
        for (int i = 0; i < 4; ++i) {
            const int idx = t + (i << 8);
            const int rr = idx >> 4, seg = idx & 15;
            const float4 kv = *(const float4*)&K[hbase + (size_t)(kv0 + rr) * D_MODEL + (seg << 2)];
            const float4 vv = *(const float4*)&V[hbase + (size_t)(kv0 + rr) * D_MODEL + (seg << 2)];
            *(float4*)&KPs[rr * 64 + SW(rr, seg)] = kv;
            *(float4*)&Vs[rr * 64 + SW(rr, seg)] = vv;
        }
        __syncthreads();
        float s[4][4];
#pragma unroll
        for (int i = 0; i < 4; ++i)
#pragma unroll
            for (int j = 0; j < 4; ++j) s[i][j] = 0.f;
#pragma unroll
        for (int seg = 0; seg < 16; ++seg) {
            float4 qv[4], kv[4];
#pragma unroll
            for (int i = 0; i < 4; ++i) {
                const int R = (ty << 2) + i;
                qv[i] = *(const float4*)&Qs[R * 64 + SW(R, seg)];
            }
#pragma unroll
            for (int j = 0; j < 4; ++j) {
                const int Cc = (tx << 2) + j;
                kv[j] = *(const float4*)&KPs[Cc * 64 + SW(Cc, seg)];
            }
#pragma unroll
            for (int i = 0; i < 4; ++i)
#pragma unroll
                for (int j = 0; j < 4; ++j)
                    s[i][j] += qv[i].x * kv[j].x + qv[i].y * kv[j].y +
                               qv[i].z * kv[j].z + qv[i].w * kv[j].w;
        }
        const bool diag = (kt == qt);
        float tm[4];
#pragma unroll
        for (int i = 0; i < 4; ++i) {
            tm[i] = -INFINITY;
#pragma unroll
            for (int j = 0; j < 4; ++j) {
                float sval = s[i][j] * 0.125f;
                if (diag) {
                    const int Cg = kv0 + (tx << 2) + j;
                    const int Rg = q0 + (ty << 2) + i;
                    if (Cg > Rg) sval = -INFINITY;
                }
                s[i][j] = sval;
                tm[i] = fmaxf(tm[i], sval);
            }
            tm[i] = fmaxf(tm[i], __shfl_xor(tm[i], 1));
            tm[i] = fmaxf(tm[i], __shfl_xor(tm[i], 2));
            tm[i] = fmaxf(tm[i], __shfl_xor(tm[i], 4));
            tm[i] = fmaxf(tm[i], __shfl_xor(tm[i], 8));
        }
        float p[4][4];
#pragma unroll
        for (int i = 0; i < 4; ++i) {
            const float mn = fmaxf(m[i], tm[i]);
            const float alpha = __expf(m[i] - mn);
            m[i] = mn;
            float psum = 0.f;
#pragma unroll
            for (int j = 0; j < 4; ++j) {
                p[i][j] = __expf(s[i][j] - mn);
                psum += p[i][j];
            }
            psum += __shfl_xor(psum, 1);
            psum += __shfl_xor(psum, 2);
            psum += __shfl_xor(psum, 4);
            psum += __shfl_xor(psum, 8);
            lr_[i] = lr_[i] * alpha + psum;
#pragma unroll
            for (int j = 0; j < 4; ++j) oacc[i][j] *= alpha;
        }
        __syncthreads();
#pragma unroll
        for (int i = 0; i < 4; ++i) {
            const int R = (ty << 2) + i;
            float4 pv;
            pv.x = p[i][0]; pv.y = p[i][1]; pv.z = p[i][2]; pv.w = p[i][3];
            *(float4*)&KPs[R * 64 + SW(R, tx)] = pv;
        }
        __syncthreads();
#pragma unroll
        for (int cs = 0; cs < 16; ++cs) {
            float pc[4][4];
            float4 vr[4];
#pragma unroll
            for (int i = 0; i < 4; ++i) {
                const int R = (ty << 2) + i;
                const float4 pr = *(const float4*)&KPs[R * 64 + SW(R, cs)];
                pc[i][0] = pr.x; pc[i][1] = pr.y; pc[i][2] = pr.z; pc[i][3] = pr.w;
            }
#pragma unroll
            for (int cc = 0; cc < 4; ++cc) {
                const int Cr = (cs << 2) + cc;
                vr[cc] = *(const float4*)&Vs[Cr * 64 + SW(Cr, tx)];
            }
#pragma unroll
            for (int i = 0; i < 4; ++i)
#pragma unroll
                for (int cc = 0; cc < 4; ++cc) {
                    oacc[i][0] += pc[i][cc] * vr[cc].x;
                    oacc[i][1] += pc[i][cc] * vr[cc].y;
                    oacc[i][2] += pc[i][cc] * vr[cc].z;
                    oacc[i][3] += pc[i][cc] * vr[cc].w;
                }
        }
    }
#pragma unroll
    for (int i = 0; i < 4; ++i) {
        const int R = (ty << 2) + i;
        const float invl = 1.0f / lr_[i];
        float4 o;
        o.x = oacc[i][0] * invl; o.y = oacc[i][1] * invl;
        o.z = oacc[i][2] * invl; o.w = oacc[i][3] * invl;
        *(float4*)&O[hbase + (size_t)(q0 + R) * D_MODEL + (tx << 2)] = o;
    }
}

// ---------------------------------------------------------------------------
extern "C" void kernel_launch(void* const* d_in, const int* in_sizes, int n_in,
                              void* d_out, int out_size, void* d_ws, size_t ws_size,
                              hipStream_t stream) {
    const float* x  = (const float*)d_in[0];
    const float* Wq = (const float*)d_in[2];
    const float* Wk = (const float*)d_in[3];
    const float* Wv = (const float*)d_in[4];
    const float* Wo = (const float*)d_in[5];
    float* out = (float*)d_out;

    if (ws_size >= 83886080ull) {
        char* ws = (char*)d_ws;
        u16* x2  = (u16*)(ws);                // 16 MB, reused as A2 after QKV
        u16* Wq2 = (u16*)(ws + 16777216);     // Wq2/Wk2/Wv2/Wo2 contiguous 4MB each
        u16* Wo2 = (u16*)(ws + 29360128);
        u16* Qh  = (u16*)(ws + 33554432);
        u16* Ql  = (u16*)(ws + 41943040);
        u16* Kh  = (u16*)(ws + 50331648);
        u16* Kl  = (u16*)(ws + 58720256);
        u16* Vth = (u16*)(ws + 67108864);
        u16* Vh  = (u16*)d_out;               // scratch, rewritten by final GEMM

        hipFuncSetAttribute((const void*)flash_mfma,
                            hipFuncAttributeMaxDynamicSharedMemorySize, 131072);
        hipFuncSetAttribute((const void*)gemm256_qkv,
                            hipFuncAttributeMaxDynamicSharedMemorySize, 114688);

        split_all<<<8192, 256, 0, stream>>>(x, Wq, Wk, Wv, Wo, x2, Wq2);
        gemm256_qkv<<<256, 512, 114688, stream>>>(x2, Wq2, Qh, Ql, Kh, Kl, Vh);
        vtrans<<<dim3(16, 16, 2), 128, 0, stream>>>(Vh, Vth);
        flash_mfma<<<256, 512, 131072, stream>>>(Qh, Ql, Kh, Kl, Vth, x2);
        gemm_wo<<<512, 256, 0, stream>>>(x2, Wo2, out);
    } else {
        const int M = B_SIZE * L_SEQ, N = D_MODEL, Kd = D_MODEL;
        float* Qw = (float*)d_ws;
        float* Kw = Qw + (size_t)M * D_MODEL;
        float* Vw = Kw + (size_t)M * D_MODEL;
        float* Aw = Vw + (size_t)M * D_MODEL;
        dim3 gg(N / 64, M / 64);
        gemm_bt_f32<<<gg, 256, 0, stream>>>(x, Wq, Qw, M, N, Kd);
        gemm_bt_f32<<<gg, 256, 0, stream>>>(x, Wk, Kw, M, N, Kd);
        gemm_bt_f32<<<gg, 256, 0, stream>>>(x, Wv, Vw, M, N, Kd);
        flash_f32<<<dim3(L_SEQ / 64, N_HEAD, B_SIZE), 256, 0, stream>>>(Qw, Kw, Vw, Aw);
        gemm_bt_f32<<<gg, 256, 0, stream>>>(Aw, Wo, out, M, N, Kd);
    }
}